// Round 6
// baseline (824.709 us; speedup 1.0000x reference)
//
#include <hip/hip_runtime.h>

typedef unsigned short u16;
typedef __attribute__((ext_vector_type(8))) short bs8;
typedef __attribute__((ext_vector_type(4))) short bs4;
typedef __attribute__((ext_vector_type(4))) float fx4;
#define MFMA16(a,b,c) __builtin_amdgcn_mfma_f32_16x16x32_bf16(a,b,c,0,0,0)

__device__ __forceinline__ float b2f(u16 u){ return __uint_as_float(((unsigned int)u) << 16); }
__device__ __forceinline__ u16 f2b(float f){
  unsigned int x = __float_as_uint(f);
  unsigned int r = (x + 0x7FFFu + ((x >> 16) & 1u)) >> 16;
  return (u16)r;
}
__device__ __forceinline__ float rcpf(float x){ return __builtin_amdgcn_rcpf(x); }
__device__ __forceinline__ float sigm(float x){ return rcpf(1.f+__expf(-x)); }
__device__ __forceinline__ float siluf(float x){ return x*rcpf(1.f+__expf(-x)); }
__device__ __forceinline__ float wsum(float v){
  #pragma unroll
  for (int o=1;o<64;o<<=1) v += __shfl_xor(v, o);
  return v;
}
__device__ __forceinline__ float wmax(float v){
  #pragma unroll
  for (int o=1;o<64;o<<=1) v = fmaxf(v, __shfl_xor(v, o));
  return v;
}
__device__ __forceinline__ bs8 lds8(const u16* ptr){ return *reinterpret_cast<const bs8*>(ptr); }
__device__ __forceinline__ bs8 glb8(const u16* ptr){ return *reinterpret_cast<const bs8*>(ptr); }

// LDS strides (elements): row pitch mod 32 banks rotates by 4
#define XSB_P 328   // [.][328] bf16 : cols 0..255 xs, 256..319 vn
#define XVB_P 72    // [.][72]  bf16 : row = c*16+node, col = d/h
#define SGB_P 264   // [.][264] bf16
#define UBUF_P 68   // [.][68]  f32
#define XQ_P 456    // [.][456] bf16 : 448 q-features
#define AT_P 72     // [.][72]  bf16 : 64 anchors

struct GP {
  const float* x_s; const float* x_v; const int* bidx;
  const float* wh[5]; const float* ws_w[5]; const float* ws_b[5];
  const float* wv[4]; const float* wsv_w[4]; const float* wsv_b[4];
  const float *w1, *b1, *lng, *lnb, *w2, *b2, *gbias;
  u16 *wsP, *whP, *wvP, *wsvP, *w1P, *w2P;   // MFMA-B-fragment packed bf16
  float *wsb_f, *wsvb_f, *b1_f, *b2_f, *lng_f, *lnb_f, *gb_f;
  // panel layouts, K-major for the compression GEMM:
  //   PT[n>>4][r(64)][n&15]  bf16     (P transposed, per-16-node panels)
  //   KP/VP[n>>4][f(448)][n&15] bf16  (K/V features f = [Ks(256) | Kv c*64+d])
  u16 *KP, *VP, *Gs, *PT, *QB;               // QB[n][448] bf16 (Q features)
  float *Gv, *CK, *CV;
  u16 *CKP, *CVP;                            // packed bf16 B-frags for attention
  int *bstart;                               // [9] batch segment starts
  float *Qs, *Qv;   // final outputs inside d_out (f32)
};

// ---------- prep: pack weights into MFMA B-fragment order, biases f32 --------
__global__ __launch_bounds__(256) void kprep(GP p){
  int idx = blockIdx.x*256 + threadIdx.x;
  if (idx < 409600){            // wsP: 5 sets, K=320 (10 ks), N=256 (16 nt)
    int s=idx/81920, r=idx%81920;
    int ks=r/8192, r2=r%8192, nt=r2/512, r3=r2%512, ln=r3/8, j=r3%8;
    int n=nt*16+(ln&15), k=ks*32+((ln>>4)*8)+j;
    p.wsP[idx] = f2b(p.ws_w[s][n*320+k]); return;
  }
  idx -= 409600;
  if (idx < 20480){             // whP: 5 sets, K=64 (2 ks), N=64 (4 nt)
    int s=idx/4096, r=idx%4096;
    int ks=r/2048, r2=r%2048, nt=r2/512, r3=r2%512, ln=r3/8, j=r3%8;
    int h=nt*16+(ln&15), d=ks*32+((ln>>4)*8)+j;
    p.whP[idx] = f2b(p.wh[s][h*64+d]); return;
  }
  idx -= 20480;
  if (idx < 16384){             // wvP: 4 sets, K=64, N=64
    int s=idx/4096, r=idx%4096;
    int ks=r/2048, r2=r%2048, nt=r2/512, r3=r2%512, ln=r3/8, j=r3%8;
    int dd=nt*16+(ln&15), hh=ks*32+((ln>>4)*8)+j;
    p.wvP[idx] = f2b(p.wv[s][dd*64+hh]); return;
  }
  idx -= 16384;
  if (idx < 65536){             // wsvP: 4 sets, K=256 (8 ks), N=64 (4 nt)
    int s=idx/16384, r=idx%16384;
    int ks=r/2048, r2=r%2048, nt=r2/512, r3=r2%512, ln=r3/8, j=r3%8;
    int dd=nt*16+(ln&15), i=ks*32+((ln>>4)*8)+j;
    p.wsvP[idx] = f2b(p.wsv_w[s][dd*256+i]); return;
  }
  idx -= 65536;
  if (idx < 65536){             // w1P: K=256 (8 ks), N=256 (16 nt)
    int ks=idx/8192, r2=idx%8192, nt=r2/512, r3=r2%512, ln=r3/8, j=r3%8;
    int n=nt*16+(ln&15), k=ks*32+((ln>>4)*8)+j;
    p.w1P[idx] = f2b(p.w1[n*256+k]); return;
  }
  idx -= 65536;
  if (idx < 16384){             // w2P: K=256 (8 ks), N=64 (4 nt)
    int ks=idx/2048, r2=idx%2048, nt=r2/512, r3=r2%512, ln=r3/8, j=r3%8;
    int rr=nt*16+(ln&15), i=ks*32+((ln>>4)*8)+j;
    p.w2P[idx] = f2b(p.w2[rr*256+i]); return;
  }
  idx -= 16384;
  if (idx < 1280){ int s=idx>>8, i=idx&255; p.wsb_f[idx] = p.ws_b[s][i]; return; }
  idx -= 1280;
  if (idx < 256){ int s=idx>>6, d=idx&63; p.wsvb_f[idx] = p.wsv_b[s][d]; return; }
  idx -= 256;
  if (idx < 256){ p.b1_f[idx] = p.b1[idx]; return; }
  idx -= 256;
  if (idx < 64){ p.b2_f[idx] = p.b2[idx]; return; }
  idx -= 64;
  if (idx < 256){ p.lng_f[idx] = p.lng[idx]; return; }
  idx -= 256;
  if (idx < 256){ p.lnb_f[idx] = p.lnb[idx]; return; }
  idx -= 256;
  if (idx < 256){ p.gb_f[idx] = p.gbias[idx]; return; }
  idx -= 256;
  if (idx < 65536){             // batch segment starts from sorted bidx
    if (idx == 0){
      int b0 = p.bidx[0];
      for (int b=0;b<=b0;b++) p.bstart[b]=0;
      int bl = p.bidx[65535];
      for (int b=bl+1;b<=8;b++) p.bstart[b]=65536;
    } else {
      int a = p.bidx[idx-1], c = p.bidx[idx];
      for (int b=a+1;b<=c;b++) p.bstart[b] = idx;
    }
    return;
  }
}

// -------- MFMA building blocks (16-node half; w4 = wave role 0..3) ----------
// vh MFMA + in-register vn: thread holds c=0,1,2 of the same (node,h) in
// a0[r],a1[r],a2[r] -> vn computed without the LDS round-trip (1 barrier saved)
__device__ __forceinline__ void mfma_vh_vn(const u16* whPs, const u16* xvb, u16* vhb2,
                                           u16* xsb, int lane, int w4){
  fx4 a0={0,0,0,0}, a1={0,0,0,0}, a2={0,0,0,0};
  #pragma unroll
  for (int ks=0; ks<2; ks++){
    bs8 b = glb8(whPs + (ks*4+w4)*512 + lane*8);
    bs8 x0 = lds8(xvb + ( 0 + (lane&15))*XVB_P + ks*32 + ((lane>>4)*8));
    bs8 x1 = lds8(xvb + (16 + (lane&15))*XVB_P + ks*32 + ((lane>>4)*8));
    bs8 x2 = lds8(xvb + (32 + (lane&15))*XVB_P + ks*32 + ((lane>>4)*8));
    a0 = MFMA16(x0,b,a0); a1 = MFMA16(x1,b,a1); a2 = MFMA16(x2,b,a2);
  }
  int h = w4*16 + (lane&15);
  int mrow = (lane>>4)*4;
  #pragma unroll
  for (int r=0;r<4;r++){
    vhb2[( 0+mrow+r)*XVB_P + h] = f2b(a0[r]);
    vhb2[(16+mrow+r)*XVB_P + h] = f2b(a1[r]);
    vhb2[(32+mrow+r)*XVB_P + h] = f2b(a2[r]);
    float nv = __builtin_amdgcn_sqrtf(
        fmaxf(a0[r]*a0[r] + a1[r]*a1[r] + a2[r]*a2[r], 1e-8f));
    xsb[(mrow+r)*XSB_P + 256 + h] = f2b(nv);
  }
  __syncthreads();
}

template<int KS>
__device__ __forceinline__ void mfma_sgemm(const u16* wsPs, const float* bias,
                                           const u16* xsb, int lane, int w4, fx4 acc[4]){
  #pragma unroll
  for (int t=0;t<4;t++) acc[t] = (fx4){0.f,0.f,0.f,0.f};
  const u16* arow = xsb + (lane&15)*XSB_P + ((lane>>4)*8);
  #pragma unroll
  for (int ks=0; ks<KS; ks++){
    bs8 a = lds8(arow + ks*32);
    #pragma unroll
    for (int t=0;t<4;t++){
      bs8 b = glb8(wsPs + (ks*16 + w4*4 + t)*512 + lane*8);
      acc[t] = MFMA16(a,b,acc[t]);
    }
  }
  #pragma unroll
  for (int t=0;t<4;t++){
    float bv = bias[(w4*4+t)*16 + (lane&15)];
    acc[t][0]+=bv; acc[t][1]+=bv; acc[t][2]+=bv; acc[t][3]+=bv;
  }
}

__device__ __forceinline__ fx4 mfma_g64(const u16* bP, const u16* sgb, int lane, int w4){
  fx4 acc = {0.f,0.f,0.f,0.f};
  const u16* arow = sgb + (lane&15)*SGB_P + ((lane>>4)*8);
  #pragma unroll
  for (int ks=0; ks<8; ks++){
    bs8 a = lds8(arow + ks*32);
    bs8 b = glb8(bP + (ks*4 + w4)*512 + lane*8);
    acc = MFMA16(a,b,acc);
  }
  return acc;
}

__device__ __forceinline__ void mfma_wv(const u16* wvPs, const u16* vhb2,
                                        int lane, int w4, fx4 vo[3]){
  vo[0]=(fx4){0.f,0.f,0.f,0.f}; vo[1]=vo[0]; vo[2]=vo[0];
  #pragma unroll
  for (int ks=0; ks<2; ks++){
    bs8 b = glb8(wvPs + (ks*4+w4)*512 + lane*8);
    #pragma unroll
    for (int c=0;c<3;c++){
      bs8 a = lds8(vhb2 + (c*16 + (lane&15))*XVB_P + ks*32 + ((lane>>4)*8));
      vo[c] = MFMA16(a,b,vo[c]);
    }
  }
}

// ------- k1: q/k/v/g GVPs + comp path (32 nodes / block, 8 waves) -----------
// LDS caps at 2 blocks/CU (= 4 waves/SIMD) -> min-waves 4 allows 128 VGPR
__global__ __launch_bounds__(512, 4) void k1(GP p){
  __shared__ __align__(16) u16 xsb[32*XSB_P];
  __shared__ __align__(16) u16 xvb[96*XVB_P];
  __shared__ __align__(16) u16 vhb2[96*XVB_P];
  __shared__ __align__(16) u16 sgb[32*SGB_P];
  __shared__ float red[2][8][16];
  __shared__ float lnp[2][2][16];
  __shared__ float ubuf[32*UBUF_P];
  const int tid = threadIdx.x, lane = tid&63, wave = tid>>6;
  const int w4 = wave&3, hv = wave>>2;
  const int ml = lane&15, gl = lane>>4;
  const int n0 = blockIdx.x * 32;
  const int nb = n0 + hv*16;
  u16* xsbH  = xsb  + hv*16*XSB_P;
  u16* xvbH  = xvb  + hv*48*XVB_P;
  u16* vhb2H = vhb2 + hv*48*XVB_P;
  u16* sgbH  = sgb  + hv*16*SGB_P;

  for (int i=tid;i<2048;i+=512){
    int node=i>>6, c4=(i&63)*4;
    float4 v = *reinterpret_cast<const float4*>(p.x_s + (size_t)(n0+node)*256 + c4);
    u16* d = xsb + node*XSB_P + c4;
    d[0]=f2b(v.x); d[1]=f2b(v.y); d[2]=f2b(v.z); d[3]=f2b(v.w);
  }
  for (int i=tid;i<6144;i+=512){
    int row=i>>6, d=i&63;
    int h=row/48, rr=row-48*h, c=rr>>4, nl=rr&15;
    xvb[row*XVB_P+d] = f2b(p.x_v[(size_t)(n0+h*16+nl)*192 + d*3 + c]);
  }
  __syncthreads();

  fx4 acc[4];
  #pragma unroll 1
  for (int s=0; s<3; ++s){      // 0=q 1=k 2=v
    mfma_vh_vn(p.whP + s*4096, xvbH, vhb2H, xsbH, lane, w4);
    mfma_sgemm<10>(p.wsP + (size_t)s*81920, p.wsb_f + s*256, xsbH, lane, w4, acc);
    #pragma unroll
    for (int t=0;t<4;t++){
      int ncol=(w4*4+t)*16+ml;
      bs4 st;
      #pragma unroll
      for (int r=0;r<4;r++){
        int node=gl*4+r;
        float v=acc[t][r];
        float sg=rcpf(1.f+__expf(-v));     // shared exp for sigmoid+silu
        u16 slb = f2b(v*sg);
        if (s==0) p.QB[(size_t)(nb+node)*448+ncol]=slb;
        else      st[r]=(short)slb;
        sgbH[node*SGB_P+ncol]=f2b(sg);
      }
      if (s!=0){
        u16* KVp = (s==1)? p.KP : p.VP;
        *reinterpret_cast<bs4*>(KVp + ((size_t)((n0>>4)+hv)*448 + ncol)*16 + gl*4) = st;
      }
    }
    __syncthreads();
    fx4 g = mfma_g64(p.wsvP + s*16384, sgbH, lane, w4);
    fx4 vo[3];
    mfma_wv(p.wvP + s*4096, vhb2H, lane, w4, vo);
    int dout = w4*16+ml;
    if (s==0){
      #pragma unroll
      for (int r=0;r<4;r++){
        int node=gl*4+r;
        float gg = sigm(g[r] + p.wsvb_f[dout]);
        #pragma unroll
        for (int c=0;c<3;c++)
          p.QB[(size_t)(nb+node)*448 + 256 + c*64 + dout] = f2b(vo[c][r]*gg);
      }
    } else {
      u16* KVp=(s==1)?p.KP:p.VP;
      float gg[4];
      #pragma unroll
      for (int r=0;r<4;r++) gg[r] = sigm(g[r] + p.wsvb_f[s*64+dout]);
      #pragma unroll
      for (int c=0;c<3;c++){
        bs4 st;
        #pragma unroll
        for (int r=0;r<4;r++) st[r]=(short)f2b(vo[c][r]*gg[r]);
        *reinterpret_cast<bs4*>(KVp + ((size_t)((n0>>4)+hv)*448 + 256 + c*64 + dout)*16 + gl*4) = st;
      }
    }
    __syncthreads();
  }

  // gate set
  mfma_vh_vn(p.whP + 3*4096, xvbH, vhb2H, xsbH, lane, w4);
  mfma_sgemm<10>(p.wsP + (size_t)3*81920, p.wsb_f + 3*256, xsbH, lane, w4, acc);
  {
    float psum[4] = {0.f,0.f,0.f,0.f};
    #pragma unroll
    for (int t=0;t<4;t++){
      int ncol=(w4*4+t)*16+ml;
      float gb = p.gb_f[ncol];
      #pragma unroll
      for (int r=0;r<4;r++){
        int node=gl*4+r;
        float gs = sigm(acc[t][r] + gb);
        p.Gs[(size_t)(nb+node)*256+ncol] = f2b(gs);
        psum[r] += gs;
      }
    }
    #pragma unroll
    for (int r=0;r<4;r++){
      #pragma unroll
      for (int o=1;o<16;o<<=1) psum[r] += __shfl_xor(psum[r], o);
    }
    if (ml==0){
      #pragma unroll
      for (int r=0;r<4;r++) red[hv][w4][gl*4+r] = psum[r];
    }
    __syncthreads();
    if (tid<32){
      int h=tid>>4, nl=tid&15;
      p.Gv[n0+tid] = sigm((red[h][0][nl]+red[h][1][nl]+red[h][2][nl]+red[h][3][nl])*(1.f/256.f));
    }
    __syncthreads();
  }

  // comp path
  mfma_sgemm<8>(p.w1P, p.b1_f, xsbH, lane, w4, acc);
  {
    float s1[4]={0.f,0.f,0.f,0.f}, s2[4]={0.f,0.f,0.f,0.f};
    #pragma unroll
    for (int t=0;t<4;t++)
      #pragma unroll
      for (int r=0;r<4;r++){ float v=acc[t][r]; s1[r]+=v; s2[r]+=v*v; }
    #pragma unroll
    for (int r=0;r<4;r++){
      #pragma unroll
      for (int o=1;o<16;o<<=1){ s1[r]+=__shfl_xor(s1[r],o); s2[r]+=__shfl_xor(s2[r],o); }
    }
    if (ml==0){
      #pragma unroll
      for (int r=0;r<4;r++){
        red[hv][w4][gl*4+r]=s1[r];
        red[hv][4+w4][gl*4+r]=s2[r];
      }
    }
    __syncthreads();
    if (tid<32){
      int h=tid>>4, nl=tid&15;
      float S1=red[h][0][nl]+red[h][1][nl]+red[h][2][nl]+red[h][3][nl];
      float S2=red[h][4][nl]+red[h][5][nl]+red[h][6][nl]+red[h][7][nl];
      float mu=S1*(1.f/256.f), var=S2*(1.f/256.f)-mu*mu;
      lnp[h][0][nl]=mu; lnp[h][1][nl]=rsqrtf(var+1e-5f);
    }
    __syncthreads();
    #pragma unroll
    for (int t=0;t<4;t++){
      int ncol=(w4*4+t)*16+ml;
      float g=p.lng_f[ncol], b=p.lnb_f[ncol];
      #pragma unroll
      for (int r=0;r<4;r++){
        int node=gl*4+r;
        float h=(acc[t][r]-lnp[hv][0][node])*lnp[hv][1][node]*g + b;
        sgbH[node*SGB_P+ncol]=f2b(siluf(h));
      }
    }
    __syncthreads();
    fx4 u = mfma_g64(p.w2P, sgbH, lane, w4);
    int rcol = w4*16+ml;
    float b2v = p.b2_f[rcol];
    #pragma unroll
    for (int r=0;r<4;r++)
      ubuf[(hv*16 + gl*4+r)*UBUF_P + rcol] = u[r] + b2v;
    __syncthreads();
    bs4 pt4;
    #pragma unroll
    for (int i=0;i<4;i++){
      int node = wave*4+i;                   // 0..31
      float uu = ubuf[node*UBUF_P + lane];
      float m = wmax(uu);
      float e = __expf(uu-m);
      float ss = wsum(e);
      pt4[i] = (short)f2b(e*rcpf(ss));
    }
    // PT[n>>4][r=lane][n&15]
    *reinterpret_cast<bs4*>(p.PT + ((size_t)((n0>>4)+(wave>>2))*64 + lane)*16 + (wave&3)*4) = pt4;
  }
}

// ---------------- k2: per-batch anchor compression via MFMA ------------------
// grid: 8 batches x {K,V} x 16 splits = 256 blocks.  CK[b][f][r] / CV[b][r][f] += P^T F
__device__ __forceinline__ bs8 ldfrag(const u16* base, int n8, int row, int stride){
  return *reinterpret_cast<const bs8*>(base + ((size_t)(n8>>4)*stride + row)*16 + (n8&15));
}

__global__ __launch_bounds__(256) void k2(GP p){
  const int bid = blockIdx.x;
  const int bb = bid >> 5;
  const int sv = (bid >> 4) & 1;      // 0 = K, 1 = V
  const int sp = bid & 15;
  const int lane = threadIdx.x & 63, wave = threadIdx.x >> 6;
  const int ml = lane & 15, gl = lane >> 4;
  int s0 = p.bstart[bb], s1 = p.bstart[bb+1];
  int len = s1 - s0; if (len <= 0) return;
  int cl = (((len + 15) >> 4) + 7) & ~7;       // per-split span, multiple of 8
  int kb0 = s0 + sp*cl; if (kb0 >= s1) return;
  int kb1 = kb0 + cl; if (kb1 > s1) kb1 = s1;
  int kba = kb0 & ~7;                          // 8-aligned fragment base
  const u16* F = sv ? p.VP : p.KP;
  fx4 acc[4][7];
  #pragma unroll
  for (int m=0;m<4;m++)
    #pragma unroll
    for (int t=0;t<7;t++) acc[m][t]=(fx4){0.f,0.f,0.f,0.f};

  for (int kb = kba; kb < kb1; kb += 32){
    int n8 = kb + gl*8;
    bool edge = (kb < kb0) | (kb + 32 > kb1);
    bs8 a[4];
    #pragma unroll
    for (int m=0;m<4;m++) a[m] = ldfrag(p.PT, n8, m*16+ml, 64);
    if (edge){
      #pragma unroll
      for (int j=0;j<8;j++){
        int n = n8 + j;
        if (n < kb0 || n >= kb1){
          #pragma unroll
          for (int m=0;m<4;m++) a[m][j]=0;
        }
      }
    }
    #pragma unroll
    for (int t=0;t<7;t++){
      bs8 bf = ldfrag(F, n8, (wave*7+t)*16+ml, 448);
      if (edge){
        #pragma unroll
        for (int j=0;j<8;j++){
          int n = n8 + j;
          if (n < kb0 || n >= kb1) bf[j]=0;
        }
      }
      #pragma unroll
      for (int m=0;m<4;m++) acc[m][t] = MFMA16(a[m], bf, acc[m][t]);
    }
  }
  #pragma unroll
  for (int m=0;m<4;m++){
    #pragma unroll
    for (int t=0;t<7;t++){
      int f = (wave*7+t)*16 + ml;
      int r0 = m*16 + gl*4;
      if (sv==0){
        float* dst = p.CK + ((size_t)bb*448+f)*64 + r0;
        #pragma unroll
        for (int j=0;j<4;j++) atomicAdd(dst+j, acc[m][t][j]);
      } else {
        float* dst = p.CV + ((size_t)bb*64+r0)*448 + f;
        #pragma unroll
        for (int j=0;j<4;j++) atomicAdd(dst + (size_t)j*448, acc[m][t][j]);
      }
    }
  }
}

// ------------- k2b: pack CK (with SCALE) and CV into bf16 B-fragments --------
// CKP[b][ks14][nt4][lane][8]: B[k=f][n=r];  CVP[b][ks2][nt28][lane][8]: B[k=r][n=f]
__global__ __launch_bounds__(256) void k2b(GP p){
  int idx = blockIdx.x*256 + threadIdx.x;
  if (idx < 229376){
    int b=idx/28672, r=idx%28672;
    int ks=r/2048, r2=r%2048, nt=r2/512, r3=r2%512, ln=r3/8, j=r3&7;
    int f=ks*32+((ln>>4)*8)+j, rr=nt*16+(ln&15);
    p.CKP[idx] = f2b(p.CK[((size_t)b*448+f)*64+rr] * 0.047245559f);
    return;
  }
  idx -= 229376;
  int b=idx/28672, r=idx%28672;
  int ks=r/14336, r2=r%14336, nt=r2/512, r3=r2%512, ln=r3/8, j=r3&7;
  int rr=ks*32+((ln>>4)*8)+j, f=nt*16+(ln&15);
  p.CVP[idx] = f2b(p.CV[((size_t)b*64+rr)*448+f]);
}

// ---- k3: MFMA attention + gating + output GVP (32 nodes / block, 8 waves) ---
__global__ __launch_bounds__(512, 4) void k3(GP p){
  __shared__ __align__(16) char smem[68608];
  u16* xq   = (u16*)smem;               // phase1: [32][XQ_P]  (29184 B)
  u16* atb  = (u16*)(smem+29184);       // phase1: [32][AT_P]  (4608 B)
  u16* xsb  = (u16*)(smem+33792);       // [32][XSB_P]         (20992 B)
  u16* xvb  = (u16*)(smem+54784);       // [96][XVB_P]         (13824 B)
  u16* vhb2 = (u16*)smem;               // phase2 [96][XVB_P]  (aliases xq)
  u16* sgb  = (u16*)(smem+13824);       // phase2 [32][SGB_P]  (aliases xq tail/atb)
  __shared__ float redm[2][4][16];
  __shared__ float reds[2][4][16];
  __shared__ int Bl[32];
  const int tid = threadIdx.x;
  const int n0 = blockIdx.x * 32;
  const int lane = tid & 63, wave = tid >> 6;
  const int w4 = wave&3, hv = wave>>2;
  const int ml = lane&15, gl = lane>>4;
  const int nb = n0 + hv*16;
  u16* xqH   = xq   + hv*16*XQ_P;
  u16* atbH  = atb  + hv*16*AT_P;
  u16* xsbH  = xsb  + hv*16*XSB_P;
  u16* xvbH  = xvb  + hv*48*XVB_P;
  u16* vhb2H = vhb2 + hv*48*XVB_P;
  u16* sgbH  = sgb  + hv*16*SGB_P;
  const int* BlH = Bl + hv*16;

  // stage Q (bf16 QB rows) straight into A-fragment LDS
  for (int idx=tid; idx<1792; idx+=512){
    int node = idx/56, q = idx-node*56;
    bs8 v = *reinterpret_cast<const bs8*>(p.QB + (size_t)(n0+node)*448 + q*8);
    *reinterpret_cast<bs8*>(xq + node*XQ_P + q*8) = v;
  }
  if (tid<32) Bl[tid] = p.bidx[n0+tid];
  __syncthreads();

  // ---- attention over the block's distinct batches (usually 1) ----
  int bb = Bl[0];
  while (true){
    fx4 lac = {0.f,0.f,0.f,0.f};
    {
      const u16* ckb = p.CKP + (size_t)bb*28672;
      const u16* arow = xqH + ml*XQ_P + gl*8;
      #pragma unroll
      for (int ks=0; ks<14; ks++){
        bs8 a = lds8(arow + ks*32);
        bs8 b = glb8(ckb + (ks*4+w4)*512 + lane*8);
        lac = MFMA16(a,b,lac);
      }
    }
    // softmax over 64 anchors per node (16-lane + cross-wave reduce per half)
    float loc[4];
    #pragma unroll
    for (int r=0;r<4;r++){
      float m = lac[r];
      #pragma unroll
      for (int o=1;o<16;o<<=1) m = fmaxf(m, __shfl_xor(m,o));
      loc[r]=m;
    }
    if (ml==0){
      #pragma unroll
      for (int r=0;r<4;r++) redm[hv][w4][gl*4+r]=loc[r];
    }
    __syncthreads();
    float e4[4];
    #pragma unroll
    for (int r=0;r<4;r++){
      int node=gl*4+r;
      float gm = fmaxf(fmaxf(redm[hv][0][node],redm[hv][1][node]),
                       fmaxf(redm[hv][2][node],redm[hv][3][node]));
      float e = __expf(lac[r]-gm);
      e4[r]=e;
      float s=e;
      #pragma unroll
      for (int o=1;o<16;o<<=1) s += __shfl_xor(s,o);
      loc[r]=s;
    }
    if (ml==0){
      #pragma unroll
      for (int r=0;r<4;r++) reds[hv][w4][gl*4+r]=loc[r];
    }
    __syncthreads();
    #pragma unroll
    for (int r=0;r<4;r++){
      int node=gl*4+r;
      float tot = reds[hv][0][node]+reds[hv][1][node]+reds[hv][2][node]+reds[hv][3][node];
      atbH[node*AT_P + w4*16 + ml] = f2b(e4[r]*rcpf(tot));
    }
    __syncthreads();
    // PV: [16 nodes] x [448 features], K=64; wave handles ntiles w4*7..+6
    {
      const u16* cvb = p.CVP + (size_t)bb*28672;
      const u16* prow = atbH + ml*AT_P + gl*8;
      bs8 a0 = lds8(prow);
      bs8 a1 = lds8(prow + 32);
      #pragma unroll
      for (int t=0;t<7;t++){
        int nt = w4*7 + t;
        fx4 pv = {0.f,0.f,0.f,0.f};
        pv = MFMA16(a0, glb8(cvb + nt*512 + lane*8), pv);
        pv = MFMA16(a1, glb8(cvb + (28+nt)*512 + lane*8), pv);
        int f = nt*16 + ml;
        #pragma unroll
        for (int r=0;r<4;r++){
          int node=gl*4+r;
          if (BlH[node]!=bb) continue;
          int n = nb+node;
          if (f < 256){
            float gs = b2f(p.Gs[(size_t)n*256+f]);
            xsbH[node*XSB_P+f] = f2b(pv[r]*gs);
          } else {
            int fm=f-256, c=fm>>6, d=fm&63;
            xvbH[(c*16+node)*XVB_P+d] = f2b(pv[r]*p.Gv[n]);
          }
        }
      }
    }
    // next distinct batch in block (uniform across threads)
    int nxt = 0x7fffffff;
    #pragma unroll
    for (int i=0;i<32;i++){ int v=Bl[i]; if (v>bb && v<nxt) nxt=v; }
    if (nxt==0x7fffffff) break;
    bb = nxt;
    __syncthreads();   // atb rewrite hazard
  }
  __syncthreads();     // xq dead; phase2 may overwrite (vhb2/sgb alias)

  // output GVP (set 4 for wh/ws, set 3 for wv/wsv)
  mfma_vh_vn(p.whP + 4*4096, xvbH, vhb2H, xsbH, lane, w4);
  fx4 acc[4];
  mfma_sgemm<10>(p.wsP + (size_t)4*81920, p.wsb_f + 4*256, xsbH, lane, w4, acc);
  #pragma unroll
  for (int t=0;t<4;t++){
    int ncol=(w4*4+t)*16+ml;
    #pragma unroll
    for (int r=0;r<4;r++){
      int node=gl*4+r;
      float v=acc[t][r];
      float sg=rcpf(1.f+__expf(-v));       // shared exp for sigmoid+silu
      p.Qs[(size_t)(nb+node)*256+ncol]=v*sg;
      sgbH[node*SGB_P+ncol]=f2b(sg);
    }
  }
  __syncthreads();
  fx4 g = mfma_g64(p.wsvP + 3*16384, sgbH, lane, w4);
  fx4 vo[3];
  mfma_wv(p.wvP + 3*4096, vhb2H, lane, w4, vo);
  int dout = w4*16+ml;
  #pragma unroll
  for (int r=0;r<4;r++){
    int node=gl*4+r;
    float gg = sigm(g[r] + p.wsvb_f[3*64+dout]);
    #pragma unroll
    for (int c=0;c<3;c++)
      p.Qv[(size_t)(nb+node)*192 + dout*3 + c] = vo[c][r]*gg;   // [N,DV,3]
  }
}

// ---------------- host ------------------------------------------------------
extern "C" void kernel_launch(void* const* d_in, const int* in_sizes, int n_in,
                              void* d_out, int out_size, void* d_ws, size_t ws_size,
                              hipStream_t stream){
  (void)in_sizes; (void)n_in; (void)out_size; (void)ws_size;
  GP p;
  p.x_s  = (const float*)d_in[0];
  p.x_v  = (const float*)d_in[1];
  p.bidx = (const int*)d_in[2];
  const int whI[5]  = {3, 9, 15, 33, 21};
  const int wswI[5] = {4, 10, 16, 34, 22};
  const int wsbI[5] = {5, 11, 17, 35, 23};
  const int wvI[4]  = {6, 12, 18, 24};
  const int wsvwI[4]= {7, 13, 19, 25};
  const int wsvbI[4]= {8, 14, 20, 26};
  for (int s=0;s<5;s++){
    p.wh[s]   = (const float*)d_in[whI[s]];
    p.ws_w[s] = (const float*)d_in[wswI[s]];
    p.ws_b[s] = (const float*)d_in[wsbI[s]];
  }
  for (int s=0;s<4;s++){
    p.wv[s]    = (const float*)d_in[wvI[s]];
    p.wsv_w[s] = (const float*)d_in[wsvwI[s]];
    p.wsv_b[s] = (const float*)d_in[wsvbI[s]];
  }
  p.w1    = (const float*)d_in[27];
  p.b1    = (const float*)d_in[28];
  p.lng   = (const float*)d_in[29];
  p.lnb   = (const float*)d_in[30];
  p.w2    = (const float*)d_in[31];
  p.b2    = (const float*)d_in[32];
  p.gbias = (const float*)d_in[36];

  char* w = (char*)d_ws;
  auto alloc = [&](size_t bytes)->char*{
    char* r = w; w += (bytes + 255) & ~(size_t)255; return r;
  };
  p.wsP   = (u16*)alloc(409600u*2);
  p.whP   = (u16*)alloc(20480u*2);
  p.wvP   = (u16*)alloc(16384u*2);
  p.wsvP  = (u16*)alloc(65536u*2);
  p.w1P   = (u16*)alloc(65536u*2);
  p.w2P   = (u16*)alloc(16384u*2);
  p.wsb_f  = (float*)alloc(1280u*4);
  p.wsvb_f = (float*)alloc(256u*4);
  p.b1_f   = (float*)alloc(256u*4);
  p.b2_f   = (float*)alloc(64u*4);
  p.lng_f  = (float*)alloc(256u*4);
  p.lnb_f  = (float*)alloc(256u*4);
  p.gb_f   = (float*)alloc(256u*4);
  p.QB = (u16*)alloc((size_t)65536*448*2);
  p.KP = (u16*)alloc((size_t)65536*448*2 + (1u<<22));  // +4MB pad for masked edge reads
  p.VP = (u16*)alloc((size_t)65536*448*2 + (1u<<22));
  p.Gs = (u16*)alloc((size_t)65536*256*2);
  p.PT = (u16*)alloc((size_t)65536*64*2 + (1u<<20));
  p.Gv = (float*)alloc((size_t)65536*4);
  p.CK = (float*)alloc((size_t)8*448*64*4);
  p.CV = (float*)alloc((size_t)8*448*64*4);
  p.CKP = (u16*)alloc((size_t)8*448*64*2);
  p.CVP = (u16*)alloc((size_t)8*448*64*2);
  p.bstart = (int*)alloc(64);
  p.Qs = (float*)d_out;
  p.Qv = (float*)d_out + (size_t)65536*256;

  hipMemsetAsync(p.CK, 0, (size_t)8*448*64*4, stream);
  hipMemsetAsync(p.CV, 0, (size_t)8*448*64*4, stream);
  kprep<<<2587, 256, 0, stream>>>(p);
  k1<<<2048, 512, 0, stream>>>(p);
  k2<<<256, 256, 0, stream>>>(p);
  k2b<<<1792, 256, 0, stream>>>(p);
  k3<<<2048, 512, 0, stream>>>(p);
}

// Round 7
// 725.817 us; speedup vs baseline: 1.1362x; 1.1362x over previous
//
#include <hip/hip_runtime.h>

typedef unsigned short u16;
typedef __attribute__((ext_vector_type(8))) short bs8;
typedef __attribute__((ext_vector_type(4))) short bs4;
typedef __attribute__((ext_vector_type(4))) float fx4;
#define MFMA16(a,b,c) __builtin_amdgcn_mfma_f32_16x16x32_bf16(a,b,c,0,0,0)

__device__ __forceinline__ float b2f(u16 u){ return __uint_as_float(((unsigned int)u) << 16); }
__device__ __forceinline__ u16 f2b(float f){
  unsigned int x = __float_as_uint(f);
  unsigned int r = (x + 0x7FFFu + ((x >> 16) & 1u)) >> 16;
  return (u16)r;
}
__device__ __forceinline__ float rcpf(float x){ return __builtin_amdgcn_rcpf(x); }
__device__ __forceinline__ float sigm(float x){ return rcpf(1.f+__expf(-x)); }
__device__ __forceinline__ float siluf(float x){ return x*rcpf(1.f+__expf(-x)); }
__device__ __forceinline__ float wsum(float v){
  #pragma unroll
  for (int o=1;o<64;o<<=1) v += __shfl_xor(v, o);
  return v;
}
__device__ __forceinline__ float wmax(float v){
  #pragma unroll
  for (int o=1;o<64;o<<=1) v = fmaxf(v, __shfl_xor(v, o));
  return v;
}
__device__ __forceinline__ bs8 lds8(const u16* ptr){ return *reinterpret_cast<const bs8*>(ptr); }
__device__ __forceinline__ bs8 glb8(const u16* ptr){ return *reinterpret_cast<const bs8*>(ptr); }

// LDS strides (elements): row pitch mod 32 banks rotates by 4
#define XSB_P 328   // [.][328] bf16 : cols 0..255 xs, 256..319 vn
#define XVB_P 72    // [.][72]  bf16 : row = c*16+node, col = d/h
#define SGB_P 264   // [.][264] bf16
#define UBUF_P 68   // [.][68]  f32
#define XQ_P 456    // [.][456] bf16 : 448 q-features
#define AT_P 72     // [.][72]  bf16 : 64 anchors

struct GP {
  const float* x_s; const float* x_v; const int* bidx;
  const float* wh[5]; const float* ws_w[5]; const float* ws_b[5];
  const float* wv[4]; const float* wsv_w[4]; const float* wsv_b[4];
  const float *w1, *b1, *lng, *lnb, *w2, *b2, *gbias;
  u16 *wsP, *whP, *wvP, *wsvP, *w1P, *w2P;   // MFMA-B-fragment packed bf16
  float *wsb_f, *wsvb_f, *b1_f, *b2_f, *lng_f, *lnb_f, *gb_f;
  u16 *KP, *VP, *Gs, *PT, *QB;               // QB[n][448] bf16 (Q features)
  float *Gv, *CK, *CV;
  u16 *CKP, *CVP;                            // packed bf16 B-frags for attention
  int *bstart;                               // [9] batch segment starts
  float *Qs, *Qv;   // final outputs inside d_out (f32)
};

// ---------- prep: pack weights into MFMA B-fragment order, biases f32 --------
__global__ __launch_bounds__(256) void kprep(GP p){
  int idx = blockIdx.x*256 + threadIdx.x;
  if (idx < 409600){            // wsP: 5 sets, K=320 (10 ks), N=256 (16 nt)
    int s=idx/81920, r=idx%81920;
    int ks=r/8192, r2=r%8192, nt=r2/512, r3=r2%512, ln=r3/8, j=r3%8;
    int n=nt*16+(ln&15), k=ks*32+((ln>>4)*8)+j;
    p.wsP[idx] = f2b(p.ws_w[s][n*320+k]); return;
  }
  idx -= 409600;
  if (idx < 20480){             // whP: 5 sets, K=64 (2 ks), N=64 (4 nt)
    int s=idx/4096, r=idx%4096;
    int ks=r/2048, r2=r%2048, nt=r2/512, r3=r2%512, ln=r3/8, j=r3%8;
    int h=nt*16+(ln&15), d=ks*32+((ln>>4)*8)+j;
    p.whP[idx] = f2b(p.wh[s][h*64+d]); return;
  }
  idx -= 20480;
  if (idx < 16384){             // wvP: 4 sets, K=64, N=64
    int s=idx/4096, r=idx%4096;
    int ks=r/2048, r2=r%2048, nt=r2/512, r3=r2%512, ln=r3/8, j=r3%8;
    int dd=nt*16+(ln&15), hh=ks*32+((ln>>4)*8)+j;
    p.wvP[idx] = f2b(p.wv[s][dd*64+hh]); return;
  }
  idx -= 16384;
  if (idx < 65536){             // wsvP: 4 sets, K=256 (8 ks), N=64 (4 nt)
    int s=idx/16384, r=idx%16384;
    int ks=r/2048, r2=r%2048, nt=r2/512, r3=r2%512, ln=r3/8, j=r3%8;
    int dd=nt*16+(ln&15), i=ks*32+((ln>>4)*8)+j;
    p.wsvP[idx] = f2b(p.wsv_w[s][dd*256+i]); return;
  }
  idx -= 65536;
  if (idx < 65536){             // w1P: K=256 (8 ks), N=256 (16 nt)
    int ks=idx/8192, r2=idx%8192, nt=r2/512, r3=r2%512, ln=r3/8, j=r3%8;
    int n=nt*16+(ln&15), k=ks*32+((ln>>4)*8)+j;
    p.w1P[idx] = f2b(p.w1[n*256+k]); return;
  }
  idx -= 65536;
  if (idx < 16384){             // w2P: K=256 (8 ks), N=64 (4 nt)
    int ks=idx/2048, r2=idx%2048, nt=r2/512, r3=r2%512, ln=r3/8, j=r3%8;
    int rr=nt*16+(ln&15), i=ks*32+((ln>>4)*8)+j;
    p.w2P[idx] = f2b(p.w2[rr*256+i]); return;
  }
  idx -= 16384;
  if (idx < 1280){ int s=idx>>8, i=idx&255; p.wsb_f[idx] = p.ws_b[s][i]; return; }
  idx -= 1280;
  if (idx < 256){ int s=idx>>6, d=idx&63; p.wsvb_f[idx] = p.wsv_b[s][d]; return; }
  idx -= 256;
  if (idx < 256){ p.b1_f[idx] = p.b1[idx]; return; }
  idx -= 256;
  if (idx < 64){ p.b2_f[idx] = p.b2[idx]; return; }
  idx -= 64;
  if (idx < 256){ p.lng_f[idx] = p.lng[idx]; return; }
  idx -= 256;
  if (idx < 256){ p.lnb_f[idx] = p.lnb[idx]; return; }
  idx -= 256;
  if (idx < 256){ p.gb_f[idx] = p.gbias[idx]; return; }
  idx -= 256;
  if (idx < 65536){             // batch segment starts from sorted bidx
    if (idx == 0){
      int b0 = p.bidx[0];
      for (int b=0;b<=b0;b++) p.bstart[b]=0;
      int bl = p.bidx[65535];
      for (int b=bl+1;b<=8;b++) p.bstart[b]=65536;
    } else {
      int a = p.bidx[idx-1], c = p.bidx[idx];
      for (int b=a+1;b<=c;b++) p.bstart[b] = idx;
    }
    return;
  }
}

// -------- MFMA building blocks ----------
// vh MFMA + in-register vn (16-node half; w4 = wave role 0..3)
__device__ __forceinline__ void mfma_vh_vn(const u16* whPs, const u16* xvb, u16* vhb2,
                                           u16* xsb, int lane, int w4){
  fx4 a0={0,0,0,0}, a1={0,0,0,0}, a2={0,0,0,0};
  #pragma unroll
  for (int ks=0; ks<2; ks++){
    bs8 b = glb8(whPs + (ks*4+w4)*512 + lane*8);
    bs8 x0 = lds8(xvb + ( 0 + (lane&15))*XVB_P + ks*32 + ((lane>>4)*8));
    bs8 x1 = lds8(xvb + (16 + (lane&15))*XVB_P + ks*32 + ((lane>>4)*8));
    bs8 x2 = lds8(xvb + (32 + (lane&15))*XVB_P + ks*32 + ((lane>>4)*8));
    a0 = MFMA16(x0,b,a0); a1 = MFMA16(x1,b,a1); a2 = MFMA16(x2,b,a2);
  }
  int h = w4*16 + (lane&15);
  int mrow = (lane>>4)*4;
  #pragma unroll
  for (int r=0;r<4;r++){
    vhb2[( 0+mrow+r)*XVB_P + h] = f2b(a0[r]);
    vhb2[(16+mrow+r)*XVB_P + h] = f2b(a1[r]);
    vhb2[(32+mrow+r)*XVB_P + h] = f2b(a2[r]);
    float nv = __builtin_amdgcn_sqrtf(
        fmaxf(a0[r]*a0[r] + a1[r]*a1[r] + a2[r]*a2[r], 1e-8f));
    xsb[(mrow+r)*XSB_P + 256 + h] = f2b(nv);
  }
  __syncthreads();
}

// register-tiled sgemm: each wave computes M=32 (both 16-node panels) x N=32
// (2 n-tiles). Per K-step: 2 LDS A-frags + 2 global B-frags -> 4 MFMA.
// Halves the global B-fragment traffic vs the old M=16 x N=64 tiling.
template<int KS>
__device__ __forceinline__ void mfma_sgemm2(const u16* wsPs, const float* bias,
                                            const u16* xsb, int lane, int wave,
                                            fx4 acc[2][2]){
  #pragma unroll
  for (int h=0;h<2;h++)
    #pragma unroll
    for (int t=0;t<2;t++) acc[h][t]=(fx4){0.f,0.f,0.f,0.f};
  const u16* arow0 = xsb + (lane&15)*XSB_P + ((lane>>4)*8);
  const u16* arow1 = arow0 + 16*XSB_P;
  #pragma unroll
  for (int ks=0; ks<KS; ks++){
    bs8 a0 = lds8(arow0 + ks*32);
    bs8 a1 = lds8(arow1 + ks*32);
    bs8 b0 = glb8(wsPs + (ks*16 + wave*2+0)*512 + lane*8);
    bs8 b1 = glb8(wsPs + (ks*16 + wave*2+1)*512 + lane*8);
    acc[0][0]=MFMA16(a0,b0,acc[0][0]); acc[0][1]=MFMA16(a0,b1,acc[0][1]);
    acc[1][0]=MFMA16(a1,b0,acc[1][0]); acc[1][1]=MFMA16(a1,b1,acc[1][1]);
  }
  #pragma unroll
  for (int t=0;t<2;t++){
    float bv = bias[(wave*2+t)*16 + (lane&15)];
    #pragma unroll
    for (int h=0;h<2;h++){
      acc[h][t][0]+=bv; acc[h][t][1]+=bv; acc[h][t][2]+=bv; acc[h][t][3]+=bv;
    }
  }
}

__device__ __forceinline__ fx4 mfma_g64(const u16* bP, const u16* sgb, int lane, int w4){
  fx4 acc = {0.f,0.f,0.f,0.f};
  const u16* arow = sgb + (lane&15)*SGB_P + ((lane>>4)*8);
  #pragma unroll
  for (int ks=0; ks<8; ks++){
    bs8 a = lds8(arow + ks*32);
    bs8 b = glb8(bP + (ks*4 + w4)*512 + lane*8);
    acc = MFMA16(a,b,acc);
  }
  return acc;
}

__device__ __forceinline__ void mfma_wv(const u16* wvPs, const u16* vhb2,
                                        int lane, int w4, fx4 vo[3]){
  vo[0]=(fx4){0.f,0.f,0.f,0.f}; vo[1]=vo[0]; vo[2]=vo[0];
  #pragma unroll
  for (int ks=0; ks<2; ks++){
    bs8 b = glb8(wvPs + (ks*4+w4)*512 + lane*8);
    #pragma unroll
    for (int c=0;c<3;c++){
      bs8 a = lds8(vhb2 + (c*16 + (lane&15))*XVB_P + ks*32 + ((lane>>4)*8));
      vo[c] = MFMA16(a,b,vo[c]);
    }
  }
}

// ------- k1: q/k/v/g GVPs + comp path (32 nodes / block, 8 waves) -----------
__global__ __launch_bounds__(512, 4) void k1(GP p){
  __shared__ __align__(16) u16 xsb[32*XSB_P];
  __shared__ __align__(16) u16 xvb[96*XVB_P];
  __shared__ __align__(16) u16 vhb2[96*XVB_P];
  __shared__ __align__(16) u16 sgb[32*SGB_P];
  __shared__ float red[2][8][16];
  __shared__ float redb[2][8][16];
  __shared__ float lnp[2][2][16];
  __shared__ float ubuf[32*UBUF_P];
  const int tid = threadIdx.x, lane = tid&63, wave = tid>>6;
  const int w4 = wave&3, hv = wave>>2;
  const int ml = lane&15, gl = lane>>4;
  const int n0 = blockIdx.x * 32;
  u16* xsbH  = xsb  + hv*16*XSB_P;
  u16* xvbH  = xvb  + hv*48*XVB_P;
  u16* vhb2H = vhb2 + hv*48*XVB_P;
  u16* sgbH  = sgb  + hv*16*SGB_P;

  for (int i=tid;i<2048;i+=512){
    int node=i>>6, c4=(i&63)*4;
    float4 v = *reinterpret_cast<const float4*>(p.x_s + (size_t)(n0+node)*256 + c4);
    u16* d = xsb + node*XSB_P + c4;
    d[0]=f2b(v.x); d[1]=f2b(v.y); d[2]=f2b(v.z); d[3]=f2b(v.w);
  }
  for (int i=tid;i<6144;i+=512){
    int row=i>>6, d=i&63;
    int h=row/48, rr=row-48*h, c=rr>>4, nl=rr&15;
    xvb[row*XVB_P+d] = f2b(p.x_v[(size_t)(n0+h*16+nl)*192 + d*3 + c]);
  }
  __syncthreads();

  fx4 acc[2][2];
  #pragma unroll 1
  for (int s=0; s<3; ++s){      // 0=q 1=k 2=v
    mfma_vh_vn(p.whP + s*4096, xvbH, vhb2H, xsbH, lane, w4);
    mfma_sgemm2<10>(p.wsP + (size_t)s*81920, p.wsb_f + s*256, xsb, lane, wave, acc);
    bs4 stv[2][2];
    #pragma unroll
    for (int h=0;h<2;h++){
      #pragma unroll
      for (int t=0;t<2;t++){
        int ncol=(wave*2+t)*16+ml;
        #pragma unroll
        for (int r=0;r<4;r++){
          int node16=gl*4+r;
          float v=acc[h][t][r];
          float sg=rcpf(1.f+__expf(-v));   // shared exp for sigmoid+silu
          stv[h][t][r]=(short)f2b(v*sg);
          sgb[(h*16+node16)*SGB_P+ncol]=f2b(sg);
        }
      }
    }
    __syncthreads();
    // deferred global stores: drain overlaps the g64+wv compute below
    if (s==0){
      #pragma unroll
      for (int h=0;h<2;h++)
        #pragma unroll
        for (int t=0;t<2;t++){
          int ncol=(wave*2+t)*16+ml;
          #pragma unroll
          for (int r=0;r<4;r++)
            p.QB[(size_t)(n0+h*16+gl*4+r)*448+ncol]=(u16)stv[h][t][r];
        }
    } else {
      u16* KVp = (s==1)? p.KP : p.VP;
      #pragma unroll
      for (int h=0;h<2;h++)
        #pragma unroll
        for (int t=0;t<2;t++){
          int ncol=(wave*2+t)*16+ml;
          *reinterpret_cast<bs4*>(KVp + ((size_t)((n0>>4)+h)*448 + ncol)*16 + gl*4) = stv[h][t];
        }
    }
    fx4 g = mfma_g64(p.wsvP + s*16384, sgbH, lane, w4);
    fx4 vo[3];
    mfma_wv(p.wvP + s*4096, vhb2H, lane, w4, vo);
    int dout = w4*16+ml;
    const int nb = n0 + hv*16;
    if (s==0){
      #pragma unroll
      for (int r=0;r<4;r++){
        int node=gl*4+r;
        float gg = sigm(g[r] + p.wsvb_f[dout]);
        #pragma unroll
        for (int c=0;c<3;c++)
          p.QB[(size_t)(nb+node)*448 + 256 + c*64 + dout] = f2b(vo[c][r]*gg);
      }
    } else {
      u16* KVp=(s==1)?p.KP:p.VP;
      float gg[4];
      #pragma unroll
      for (int r=0;r<4;r++) gg[r] = sigm(g[r] + p.wsvb_f[s*64+dout]);
      #pragma unroll
      for (int c=0;c<3;c++){
        bs4 st;
        #pragma unroll
        for (int r=0;r<4;r++) st[r]=(short)f2b(vo[c][r]*gg[r]);
        *reinterpret_cast<bs4*>(KVp + ((size_t)((n0>>4)+hv)*448 + 256 + c*64 + dout)*16 + gl*4) = st;
      }
    }
    __syncthreads();
  }

  // gate set
  mfma_vh_vn(p.whP + 3*4096, xvbH, vhb2H, xsbH, lane, w4);
  mfma_sgemm2<10>(p.wsP + (size_t)3*81920, p.wsb_f + 3*256, xsb, lane, wave, acc);
  {
    float psum[2][4] = {{0.f,0.f,0.f,0.f},{0.f,0.f,0.f,0.f}};
    u16 gsv[2][2][4];
    #pragma unroll
    for (int h=0;h<2;h++){
      #pragma unroll
      for (int t=0;t<2;t++){
        int ncol=(wave*2+t)*16+ml;
        float gb = p.gb_f[ncol];
        #pragma unroll
        for (int r=0;r<4;r++){
          float gs = sigm(acc[h][t][r] + gb);
          gsv[h][t][r]=f2b(gs);
          psum[h][r] += gs;
        }
      }
    }
    #pragma unroll
    for (int h=0;h<2;h++)
      #pragma unroll
      for (int r=0;r<4;r++){
        #pragma unroll
        for (int o=1;o<16;o<<=1) psum[h][r] += __shfl_xor(psum[h][r], o);
      }
    if (ml==0){
      #pragma unroll
      for (int h=0;h<2;h++)
        #pragma unroll
        for (int r=0;r<4;r++) red[h][wave][gl*4+r] = psum[h][r];
    }
    __syncthreads();
    // deferred Gs stores
    #pragma unroll
    for (int h=0;h<2;h++)
      #pragma unroll
      for (int t=0;t<2;t++){
        int ncol=(wave*2+t)*16+ml;
        #pragma unroll
        for (int r=0;r<4;r++)
          p.Gs[(size_t)(n0+h*16+gl*4+r)*256+ncol] = gsv[h][t][r];
      }
    if (tid<32){
      int h=tid>>4, nl=tid&15;
      float s8 = red[h][0][nl]+red[h][1][nl]+red[h][2][nl]+red[h][3][nl]
               + red[h][4][nl]+red[h][5][nl]+red[h][6][nl]+red[h][7][nl];
      p.Gv[n0+tid] = sigm(s8*(1.f/256.f));
    }
    __syncthreads();
  }

  // comp path
  mfma_sgemm2<8>(p.w1P, p.b1_f, xsb, lane, wave, acc);
  {
    float s1[2][4]={{0.f,0.f,0.f,0.f},{0.f,0.f,0.f,0.f}};
    float s2[2][4]={{0.f,0.f,0.f,0.f},{0.f,0.f,0.f,0.f}};
    #pragma unroll
    for (int h=0;h<2;h++)
      #pragma unroll
      for (int t=0;t<2;t++)
        #pragma unroll
        for (int r=0;r<4;r++){ float v=acc[h][t][r]; s1[h][r]+=v; s2[h][r]+=v*v; }
    #pragma unroll
    for (int h=0;h<2;h++)
      #pragma unroll
      for (int r=0;r<4;r++){
        #pragma unroll
        for (int o=1;o<16;o<<=1){ s1[h][r]+=__shfl_xor(s1[h][r],o); s2[h][r]+=__shfl_xor(s2[h][r],o); }
      }
    if (ml==0){
      #pragma unroll
      for (int h=0;h<2;h++)
        #pragma unroll
        for (int r=0;r<4;r++){
          red[h][wave][gl*4+r]=s1[h][r];
          redb[h][wave][gl*4+r]=s2[h][r];
        }
    }
    __syncthreads();
    if (tid<32){
      int h=tid>>4, nl=tid&15;
      float S1=red[h][0][nl]+red[h][1][nl]+red[h][2][nl]+red[h][3][nl]
             + red[h][4][nl]+red[h][5][nl]+red[h][6][nl]+red[h][7][nl];
      float S2=redb[h][0][nl]+redb[h][1][nl]+redb[h][2][nl]+redb[h][3][nl]
             + redb[h][4][nl]+redb[h][5][nl]+redb[h][6][nl]+redb[h][7][nl];
      float mu=S1*(1.f/256.f), var=S2*(1.f/256.f)-mu*mu;
      lnp[h][0][nl]=mu; lnp[h][1][nl]=rsqrtf(var+1e-5f);
    }
    __syncthreads();
    #pragma unroll
    for (int h=0;h<2;h++)
      #pragma unroll
      for (int t=0;t<2;t++){
        int ncol=(wave*2+t)*16+ml;
        float g=p.lng_f[ncol], b=p.lnb_f[ncol];
        #pragma unroll
        for (int r=0;r<4;r++){
          int node16=gl*4+r;
          float hh=(acc[h][t][r]-lnp[h][0][node16])*lnp[h][1][node16]*g + b;
          sgb[(h*16+node16)*SGB_P+ncol]=f2b(siluf(hh));
        }
      }
    __syncthreads();
    fx4 u = mfma_g64(p.w2P, sgbH, lane, w4);
    int rcol = w4*16+ml;
    float b2v = p.b2_f[rcol];
    #pragma unroll
    for (int r=0;r<4;r++)
      ubuf[(hv*16 + gl*4+r)*UBUF_P + rcol] = u[r] + b2v;
    __syncthreads();
    bs4 pt4;
    #pragma unroll
    for (int i=0;i<4;i++){
      int node = wave*4+i;                   // 0..31
      float uu = ubuf[node*UBUF_P + lane];
      float m = wmax(uu);
      float e = __expf(uu-m);
      float ss = wsum(e);
      pt4[i] = (short)f2b(e*rcpf(ss));
    }
    // PT[n>>4][r=lane][n&15]
    *reinterpret_cast<bs4*>(p.PT + ((size_t)((n0>>4)+(wave>>2))*64 + lane)*16 + (wave&3)*4) = pt4;
  }
}

// ---------------- k2: per-batch anchor compression via MFMA ------------------
__device__ __forceinline__ bs8 ldfrag(const u16* base, int n8, int row, int stride){
  return *reinterpret_cast<const bs8*>(base + ((size_t)(n8>>4)*stride + row)*16 + (n8&15));
}

__global__ __launch_bounds__(256) void k2(GP p){
  const int bid = blockIdx.x;
  const int bb = bid >> 5;
  const int sv = (bid >> 4) & 1;      // 0 = K, 1 = V
  const int sp = bid & 15;
  const int lane = threadIdx.x & 63, wave = threadIdx.x >> 6;
  const int ml = lane & 15, gl = lane >> 4;
  int s0 = p.bstart[bb], s1 = p.bstart[bb+1];
  int len = s1 - s0; if (len <= 0) return;
  int cl = (((len + 15) >> 4) + 7) & ~7;       // per-split span, multiple of 8
  int kb0 = s0 + sp*cl; if (kb0 >= s1) return;
  int kb1 = kb0 + cl; if (kb1 > s1) kb1 = s1;
  int kba = kb0 & ~7;                          // 8-aligned fragment base
  const u16* F = sv ? p.VP : p.KP;
  fx4 acc[4][7];
  #pragma unroll
  for (int m=0;m<4;m++)
    #pragma unroll
    for (int t=0;t<7;t++) acc[m][t]=(fx4){0.f,0.f,0.f,0.f};

  for (int kb = kba; kb < kb1; kb += 32){
    int n8 = kb + gl*8;
    bool edge = (kb < kb0) | (kb + 32 > kb1);
    bs8 a[4];
    #pragma unroll
    for (int m=0;m<4;m++) a[m] = ldfrag(p.PT, n8, m*16+ml, 64);
    if (edge){
      #pragma unroll
      for (int j=0;j<8;j++){
        int n = n8 + j;
        if (n < kb0 || n >= kb1){
          #pragma unroll
          for (int m=0;m<4;m++) a[m][j]=0;
        }
      }
    }
    #pragma unroll
    for (int t=0;t<7;t++){
      bs8 bf = ldfrag(F, n8, (wave*7+t)*16+ml, 448);
      if (edge){
        #pragma unroll
        for (int j=0;j<8;j++){
          int n = n8 + j;
          if (n < kb0 || n >= kb1) bf[j]=0;
        }
      }
      #pragma unroll
      for (int m=0;m<4;m++) acc[m][t] = MFMA16(a[m], bf, acc[m][t]);
    }
  }
  #pragma unroll
  for (int m=0;m<4;m++){
    #pragma unroll
    for (int t=0;t<7;t++){
      int f = (wave*7+t)*16 + ml;
      int r0 = m*16 + gl*4;
      if (sv==0){
        float* dst = p.CK + ((size_t)bb*448+f)*64 + r0;
        #pragma unroll
        for (int j=0;j<4;j++) atomicAdd(dst+j, acc[m][t][j]);
      } else {
        float* dst = p.CV + ((size_t)bb*64+r0)*448 + f;
        #pragma unroll
        for (int j=0;j<4;j++) atomicAdd(dst + (size_t)j*448, acc[m][t][j]);
      }
    }
  }
}

// ------------- k2b: pack CK (with SCALE) and CV into bf16 B-fragments --------
__global__ __launch_bounds__(256) void k2b(GP p){
  int idx = blockIdx.x*256 + threadIdx.x;
  if (idx < 229376){
    int b=idx/28672, r=idx%28672;
    int ks=r/2048, r2=r%2048, nt=r2/512, r3=r2%512, ln=r3/8, j=r3&7;
    int f=ks*32+((ln>>4)*8)+j, rr=nt*16+(ln&15);
    p.CKP[idx] = f2b(p.CK[((size_t)b*448+f)*64+rr] * 0.047245559f);
    return;
  }
  idx -= 229376;
  int b=idx/28672, r=idx%28672;
  int ks=r/14336, r2=r%14336, nt=r2/512, r3=r2%512, ln=r3/8, j=r3&7;
  int rr=ks*32+((ln>>4)*8)+j, f=nt*16+(ln&15);
  p.CVP[idx] = f2b(p.CV[((size_t)b*64+rr)*448+f]);
}

// ---- k3: MFMA attention + gating + output GVP (32 nodes / block, 8 waves) ---
__global__ __launch_bounds__(512, 4) void k3(GP p){
  __shared__ __align__(16) char smem[68608];
  u16* xq   = (u16*)smem;               // phase1: [32][XQ_P]  (29184 B)
  u16* atb  = (u16*)(smem+29184);       // phase1: [32][AT_P]  (4608 B)
  u16* xsb  = (u16*)(smem+33792);       // [32][XSB_P]         (20992 B)
  u16* xvb  = (u16*)(smem+54784);       // [96][XVB_P]         (13824 B)
  u16* vhb2 = (u16*)smem;               // phase2 [96][XVB_P]  (aliases xq)
  u16* sgb  = (u16*)(smem+13824);       // phase2 [32][SGB_P]  (aliases xq tail/atb)
  __shared__ float redm[2][4][16];
  __shared__ float reds[2][4][16];
  __shared__ int Bl[32];
  const int tid = threadIdx.x;
  const int n0 = blockIdx.x * 32;
  const int lane = tid & 63, wave = tid >> 6;
  const int w4 = wave&3, hv = wave>>2;
  const int ml = lane&15, gl = lane>>4;
  const int nb = n0 + hv*16;
  u16* xqH   = xq   + hv*16*XQ_P;
  u16* atbH  = atb  + hv*16*AT_P;
  u16* xsbH  = xsb  + hv*16*XSB_P;
  u16* xvbH  = xvb  + hv*48*XVB_P;
  u16* vhb2H = vhb2 + hv*48*XVB_P;
  u16* sgbH  = sgb  + hv*16*SGB_P;
  const int* BlH = Bl + hv*16;

  // stage Q (bf16 QB rows) straight into A-fragment LDS
  for (int idx=tid; idx<1792; idx+=512){
    int node = idx/56, q = idx-node*56;
    bs8 v = *reinterpret_cast<const bs8*>(p.QB + (size_t)(n0+node)*448 + q*8);
    *reinterpret_cast<bs8*>(xq + node*XQ_P + q*8) = v;
  }
  if (tid<32) Bl[tid] = p.bidx[n0+tid];
  __syncthreads();

  // ---- attention over the block's distinct batches (usually 1) ----
  int bb = Bl[0];
  while (true){
    fx4 lac = {0.f,0.f,0.f,0.f};
    {
      const u16* ckb = p.CKP + (size_t)bb*28672;
      const u16* arow = xqH + ml*XQ_P + gl*8;
      #pragma unroll
      for (int ks=0; ks<14; ks++){
        bs8 a = lds8(arow + ks*32);
        bs8 b = glb8(ckb + (ks*4+w4)*512 + lane*8);
        lac = MFMA16(a,b,lac);
      }
    }
    // softmax over 64 anchors per node (16-lane + cross-wave reduce per half)
    float loc[4];
    #pragma unroll
    for (int r=0;r<4;r++){
      float m = lac[r];
      #pragma unroll
      for (int o=1;o<16;o<<=1) m = fmaxf(m, __shfl_xor(m,o));
      loc[r]=m;
    }
    if (ml==0){
      #pragma unroll
      for (int r=0;r<4;r++) redm[hv][w4][gl*4+r]=loc[r];
    }
    __syncthreads();
    float e4[4];
    #pragma unroll
    for (int r=0;r<4;r++){
      int node=gl*4+r;
      float gm = fmaxf(fmaxf(redm[hv][0][node],redm[hv][1][node]),
                       fmaxf(redm[hv][2][node],redm[hv][3][node]));
      float e = __expf(lac[r]-gm);
      e4[r]=e;
      float s=e;
      #pragma unroll
      for (int o=1;o<16;o<<=1) s += __shfl_xor(s,o);
      loc[r]=s;
    }
    if (ml==0){
      #pragma unroll
      for (int r=0;r<4;r++) reds[hv][w4][gl*4+r]=loc[r];
    }
    __syncthreads();
    #pragma unroll
    for (int r=0;r<4;r++){
      int node=gl*4+r;
      float tot = reds[hv][0][node]+reds[hv][1][node]+reds[hv][2][node]+reds[hv][3][node];
      atbH[node*AT_P + w4*16 + ml] = f2b(e4[r]*rcpf(tot));
    }
    __syncthreads();
    // PV: [16 nodes] x [448 features], K=64; wave handles ntiles w4*7..+6
    {
      const u16* cvb = p.CVP + (size_t)bb*28672;
      const u16* prow = atbH + ml*AT_P + gl*8;
      bs8 a0 = lds8(prow);
      bs8 a1 = lds8(prow + 32);
      #pragma unroll
      for (int t=0;t<7;t++){
        int nt = w4*7 + t;
        fx4 pv = {0.f,0.f,0.f,0.f};
        pv = MFMA16(a0, glb8(cvb + nt*512 + lane*8), pv);
        pv = MFMA16(a1, glb8(cvb + (28+nt)*512 + lane*8), pv);
        int f = nt*16 + ml;
        #pragma unroll
        for (int r=0;r<4;r++){
          int node=gl*4+r;
          if (BlH[node]!=bb) continue;
          int n = nb+node;
          if (f < 256){
            float gs = b2f(p.Gs[(size_t)n*256+f]);
            xsbH[node*XSB_P+f] = f2b(pv[r]*gs);
          } else {
            int fm=f-256, c=fm>>6, d=fm&63;
            xvbH[(c*16+node)*XVB_P+d] = f2b(pv[r]*p.Gv[n]);
          }
        }
      }
    }
    // next distinct batch in block (uniform across threads)
    int nxt = 0x7fffffff;
    #pragma unroll
    for (int i=0;i<32;i++){ int v=Bl[i]; if (v>bb && v<nxt) nxt=v; }
    if (nxt==0x7fffffff) break;
    bb = nxt;
    __syncthreads();   // atb rewrite hazard
  }
  __syncthreads();     // xq dead; phase2 may overwrite (vhb2/sgb alias)

  // output GVP (set 4 for wh/ws, set 3 for wv/wsv)
  mfma_vh_vn(p.whP + 4*4096, xvbH, vhb2H, xsbH, lane, w4);
  fx4 acc[2][2];
  mfma_sgemm2<10>(p.wsP + (size_t)4*81920, p.wsb_f + 4*256, xsb, lane, wave, acc);
  #pragma unroll
  for (int h=0;h<2;h++){
    #pragma unroll
    for (int t=0;t<2;t++){
      int ncol=(wave*2+t)*16+ml;
      #pragma unroll
      for (int r=0;r<4;r++){
        int node16=gl*4+r;
        float v=acc[h][t][r];
        float sg=rcpf(1.f+__expf(-v));     // shared exp for sigmoid+silu
        p.Qs[(size_t)(n0+h*16+node16)*256+ncol]=v*sg;
        sgb[(h*16+node16)*SGB_P+ncol]=f2b(sg);
      }
    }
  }
  __syncthreads();
  fx4 g = mfma_g64(p.wsvP + 3*16384, sgbH, lane, w4);
  fx4 vo[3];
  mfma_wv(p.wvP + 3*4096, vhb2H, lane, w4, vo);
  int dout = w4*16+ml;
  #pragma unroll
  for (int r=0;r<4;r++){
    int node=gl*4+r;
    float gg = sigm(g[r] + p.wsvb_f[3*64+dout]);
    #pragma unroll
    for (int c=0;c<3;c++)
      p.Qv[(size_t)(nb+node)*192 + dout*3 + c] = vo[c][r]*gg;   // [N,DV,3]
  }
}

// ---------------- host ------------------------------------------------------
extern "C" void kernel_launch(void* const* d_in, const int* in_sizes, int n_in,
                              void* d_out, int out_size, void* d_ws, size_t ws_size,
                              hipStream_t stream){
  (void)in_sizes; (void)n_in; (void)out_size; (void)ws_size;
  GP p;
  p.x_s  = (const float*)d_in[0];
  p.x_v  = (const float*)d_in[1];
  p.bidx = (const int*)d_in[2];
  const int whI[5]  = {3, 9, 15, 33, 21};
  const int wswI[5] = {4, 10, 16, 34, 22};
  const int wsbI[5] = {5, 11, 17, 35, 23};
  const int wvI[4]  = {6, 12, 18, 24};
  const int wsvwI[4]= {7, 13, 19, 25};
  const int wsvbI[4]= {8, 14, 20, 26};
  for (int s=0;s<5;s++){
    p.wh[s]   = (const float*)d_in[whI[s]];
    p.ws_w[s] = (const float*)d_in[wswI[s]];
    p.ws_b[s] = (const float*)d_in[wsbI[s]];
  }
  for (int s=0;s<4;s++){
    p.wv[s]    = (const float*)d_in[wvI[s]];
    p.wsv_w[s] = (const float*)d_in[wsvwI[s]];
    p.wsv_b[s] = (const float*)d_in[wsvbI[s]];
  }
  p.w1    = (const float*)d_in[27];
  p.b1    = (const float*)d_in[28];
  p.lng   = (const float*)d_in[29];
  p.lnb   = (const float*)d_in[30];
  p.w2    = (const float*)d_in[31];
  p.b2    = (const float*)d_in[32];
  p.gbias = (const float*)d_in[36];

  char* w = (char*)d_ws;
  auto alloc = [&](size_t bytes)->char*{
    char* r = w; w += (bytes + 255) & ~(size_t)255; return r;
  };
  p.wsP   = (u16*)alloc(409600u*2);
  p.whP   = (u16*)alloc(20480u*2);
  p.wvP   = (u16*)alloc(16384u*2);
  p.wsvP  = (u16*)alloc(65536u*2);
  p.w1P   = (u16*)alloc(65536u*2);
  p.w2P   = (u16*)alloc(16384u*2);
  p.wsb_f  = (float*)alloc(1280u*4);
  p.wsvb_f = (float*)alloc(256u*4);
  p.b1_f   = (float*)alloc(256u*4);
  p.b2_f   = (float*)alloc(64u*4);
  p.lng_f  = (float*)alloc(256u*4);
  p.lnb_f  = (float*)alloc(256u*4);
  p.gb_f   = (float*)alloc(256u*4);
  p.QB = (u16*)alloc((size_t)65536*448*2);
  p.KP = (u16*)alloc((size_t)65536*448*2 + (1u<<22));  // +4MB pad for masked edge reads
  p.VP = (u16*)alloc((size_t)65536*448*2 + (1u<<22));
  p.Gs = (u16*)alloc((size_t)65536*256*2);
  p.PT = (u16*)alloc((size_t)65536*64*2 + (1u<<20));
  p.Gv = (float*)alloc((size_t)65536*4);
  p.CK = (float*)alloc((size_t)8*448*64*4);
  p.CV = (float*)alloc((size_t)8*448*64*4);
  p.CKP = (u16*)alloc((size_t)8*448*64*2);
  p.CVP = (u16*)alloc((size_t)8*448*64*2);
  p.bstart = (int*)alloc(64);
  p.Qs = (float*)d_out;
  p.Qv = (float*)d_out + (size_t)65536*256;

  hipMemsetAsync(p.CK, 0, (size_t)8*448*64*4, stream);
  hipMemsetAsync(p.CV, 0, (size_t)8*448*64*4, stream);
  kprep<<<2587, 256, 0, stream>>>(p);
  k1<<<2048, 512, 0, stream>>>(p);
  k2<<<256, 256, 0, stream>>>(p);
  k2b<<<1792, 256, 0, stream>>>(p);
  k3<<<2048, 512, 0, stream>>>(p);
}

// Round 8
// 687.021 us; speedup vs baseline: 1.2004x; 1.0565x over previous
//
#include <hip/hip_runtime.h>

typedef unsigned short u16;
typedef __attribute__((ext_vector_type(8))) short bs8;
typedef __attribute__((ext_vector_type(4))) short bs4;
typedef __attribute__((ext_vector_type(4))) float fx4;
#define MFMA16(a,b,c) __builtin_amdgcn_mfma_f32_16x16x32_bf16(a,b,c,0,0,0)

__device__ __forceinline__ float b2f(u16 u){ return __uint_as_float(((unsigned int)u) << 16); }
__device__ __forceinline__ u16 f2b(float f){
  unsigned int x = __float_as_uint(f);
  unsigned int r = (x + 0x7FFFu + ((x >> 16) & 1u)) >> 16;
  return (u16)r;
}
__device__ __forceinline__ float rcpf(float x){ return __builtin_amdgcn_rcpf(x); }
__device__ __forceinline__ float sigm(float x){ return rcpf(1.f+__expf(-x)); }
__device__ __forceinline__ float siluf(float x){ return x*rcpf(1.f+__expf(-x)); }
__device__ __forceinline__ float wsum(float v){
  #pragma unroll
  for (int o=1;o<64;o<<=1) v += __shfl_xor(v, o);
  return v;
}
__device__ __forceinline__ float wmax(float v){
  #pragma unroll
  for (int o=1;o<64;o<<=1) v = fmaxf(v, __shfl_xor(v, o));
  return v;
}
__device__ __forceinline__ bs8 lds8(const u16* ptr){ return *reinterpret_cast<const bs8*>(ptr); }
__device__ __forceinline__ bs8 glb8(const u16* ptr){ return *reinterpret_cast<const bs8*>(ptr); }

// LDS strides (elements): row pitch mod 32 banks rotates by 4
#define XSB_P 328   // [.][328] bf16 : cols 0..255 xs, 256..319 vn
#define XVB_P 72    // [.][72]  bf16 : row = c*16+node, col = d/h
#define SGB_P 264   // [.][264] bf16
#define UBUF_P 68   // [.][68]  f32
#define XQ_P 456    // [.][456] bf16 : 448 q-features
#define AT_P 72     // [.][72]  bf16 : 64 anchors

struct GP {
  const float* x_s; const float* x_v; const int* bidx;
  const float* wh[5]; const float* ws_w[5]; const float* ws_b[5];
  const float* wv[4]; const float* wsv_w[4]; const float* wsv_b[4];
  const float *w1, *b1, *lng, *lnb, *w2, *b2, *gbias;
  u16 *wsP, *whP, *wvP, *wsvP, *w1P, *w2P;   // MFMA-B-fragment packed bf16
  float *wsb_f, *wsvb_f, *b1_f, *b2_f, *lng_f, *lnb_f, *gb_f;
  u16 *KP, *VP, *Gs, *PT, *QB;               // QB[n][448] bf16 (Q features)
  float *Gv, *CK, *CV;
  u16 *CKP, *CVP;                            // packed bf16 B-frags for attention
  int *bstart;                               // [9] batch segment starts
  float *Qs, *Qv;   // final outputs inside d_out (f32)
};

// ---------- prep: pack weights into MFMA B-fragment order, biases f32 --------
__global__ __launch_bounds__(256) void kprep(GP p){
  int idx = blockIdx.x*256 + threadIdx.x;
  if (idx < 409600){            // wsP: 5 sets, K=320 (10 ks), N=256 (16 nt)
    int s=idx/81920, r=idx%81920;
    int ks=r/8192, r2=r%8192, nt=r2/512, r3=r2%512, ln=r3/8, j=r3%8;
    int n=nt*16+(ln&15), k=ks*32+((ln>>4)*8)+j;
    p.wsP[idx] = f2b(p.ws_w[s][n*320+k]); return;
  }
  idx -= 409600;
  if (idx < 20480){             // whP: 5 sets, K=64 (2 ks), N=64 (4 nt)
    int s=idx/4096, r=idx%4096;
    int ks=r/2048, r2=r%2048, nt=r2/512, r3=r2%512, ln=r3/8, j=r3%8;
    int h=nt*16+(ln&15), d=ks*32+((ln>>4)*8)+j;
    p.whP[idx] = f2b(p.wh[s][h*64+d]); return;
  }
  idx -= 20480;
  if (idx < 16384){             // wvP: 4 sets, K=64, N=64
    int s=idx/4096, r=idx%4096;
    int ks=r/2048, r2=r%2048, nt=r2/512, r3=r2%512, ln=r3/8, j=r3%8;
    int dd=nt*16+(ln&15), hh=ks*32+((ln>>4)*8)+j;
    p.wvP[idx] = f2b(p.wv[s][dd*64+hh]); return;
  }
  idx -= 16384;
  if (idx < 65536){             // wsvP: 4 sets, K=256 (8 ks), N=64 (4 nt)
    int s=idx/16384, r=idx%16384;
    int ks=r/2048, r2=r%2048, nt=r2/512, r3=r2%512, ln=r3/8, j=r3%8;
    int dd=nt*16+(ln&15), i=ks*32+((ln>>4)*8)+j;
    p.wsvP[idx] = f2b(p.wsv_w[s][dd*256+i]); return;
  }
  idx -= 65536;
  if (idx < 65536){             // w1P: K=256 (8 ks), N=256 (16 nt)
    int ks=idx/8192, r2=idx%8192, nt=r2/512, r3=r2%512, ln=r3/8, j=r3%8;
    int n=nt*16+(ln&15), k=ks*32+((ln>>4)*8)+j;
    p.w1P[idx] = f2b(p.w1[n*256+k]); return;
  }
  idx -= 65536;
  if (idx < 16384){             // w2P: K=256 (8 ks), N=64 (4 nt)
    int ks=idx/2048, r2=idx%2048, nt=r2/512, r3=r2%512, ln=r3/8, j=r3%8;
    int rr=nt*16+(ln&15), i=ks*32+((ln>>4)*8)+j;
    p.w2P[idx] = f2b(p.w2[rr*256+i]); return;
  }
  idx -= 16384;
  if (idx < 1280){ int s=idx>>8, i=idx&255; p.wsb_f[idx] = p.ws_b[s][i]; return; }
  idx -= 1280;
  if (idx < 256){ int s=idx>>6, d=idx&63; p.wsvb_f[idx] = p.wsv_b[s][d]; return; }
  idx -= 256;
  if (idx < 256){ p.b1_f[idx] = p.b1[idx]; return; }
  idx -= 256;
  if (idx < 64){ p.b2_f[idx] = p.b2[idx]; return; }
  idx -= 64;
  if (idx < 256){ p.lng_f[idx] = p.lng[idx]; return; }
  idx -= 256;
  if (idx < 256){ p.lnb_f[idx] = p.lnb[idx]; return; }
  idx -= 256;
  if (idx < 256){ p.gb_f[idx] = p.gbias[idx]; return; }
  idx -= 256;
  if (idx < 65536){             // batch segment starts from sorted bidx
    if (idx == 0){
      int b0 = p.bidx[0];
      for (int b=0;b<=b0;b++) p.bstart[b]=0;
      int bl = p.bidx[65535];
      for (int b=bl+1;b<=8;b++) p.bstart[b]=65536;
    } else {
      int a = p.bidx[idx-1], c = p.bidx[idx];
      for (int b=a+1;b<=c;b++) p.bstart[b] = idx;
    }
    return;
  }
}

// -------- MFMA building blocks ----------
// vh MFMA + in-register vn (16-node half; w4 = wave role 0..3)
__device__ __forceinline__ void mfma_vh_vn(const u16* whPs, const u16* xvb, u16* vhb2,
                                           u16* xsb, int lane, int w4){
  fx4 a0={0,0,0,0}, a1={0,0,0,0}, a2={0,0,0,0};
  #pragma unroll
  for (int ks=0; ks<2; ks++){
    bs8 b = glb8(whPs + (ks*4+w4)*512 + lane*8);
    bs8 x0 = lds8(xvb + ( 0 + (lane&15))*XVB_P + ks*32 + ((lane>>4)*8));
    bs8 x1 = lds8(xvb + (16 + (lane&15))*XVB_P + ks*32 + ((lane>>4)*8));
    bs8 x2 = lds8(xvb + (32 + (lane&15))*XVB_P + ks*32 + ((lane>>4)*8));
    a0 = MFMA16(x0,b,a0); a1 = MFMA16(x1,b,a1); a2 = MFMA16(x2,b,a2);
  }
  int h = w4*16 + (lane&15);
  int mrow = (lane>>4)*4;
  #pragma unroll
  for (int r=0;r<4;r++){
    vhb2[( 0+mrow+r)*XVB_P + h] = f2b(a0[r]);
    vhb2[(16+mrow+r)*XVB_P + h] = f2b(a1[r]);
    vhb2[(32+mrow+r)*XVB_P + h] = f2b(a2[r]);
    float nv = __builtin_amdgcn_sqrtf(
        fmaxf(a0[r]*a0[r] + a1[r]*a1[r] + a2[r]*a2[r], 1e-8f));
    xsb[(mrow+r)*XSB_P + 256 + h] = f2b(nv);
  }
  __syncthreads();
}

// register-tiled sgemm: each wave computes M=32 (both 16-node panels) x N=32
// (2 n-tiles). Per K-step: 2 LDS A-frags + 2 global B-frags -> 4 MFMA.
template<int KS>
__device__ __forceinline__ void mfma_sgemm2(const u16* wsPs, const float* bias,
                                            const u16* xsb, int lane, int wave,
                                            fx4 acc[2][2]){
  #pragma unroll
  for (int h=0;h<2;h++)
    #pragma unroll
    for (int t=0;t<2;t++) acc[h][t]=(fx4){0.f,0.f,0.f,0.f};
  const u16* arow0 = xsb + (lane&15)*XSB_P + ((lane>>4)*8);
  const u16* arow1 = arow0 + 16*XSB_P;
  #pragma unroll
  for (int ks=0; ks<KS; ks++){
    bs8 a0 = lds8(arow0 + ks*32);
    bs8 a1 = lds8(arow1 + ks*32);
    bs8 b0 = glb8(wsPs + (ks*16 + wave*2+0)*512 + lane*8);
    bs8 b1 = glb8(wsPs + (ks*16 + wave*2+1)*512 + lane*8);
    acc[0][0]=MFMA16(a0,b0,acc[0][0]); acc[0][1]=MFMA16(a0,b1,acc[0][1]);
    acc[1][0]=MFMA16(a1,b0,acc[1][0]); acc[1][1]=MFMA16(a1,b1,acc[1][1]);
  }
  #pragma unroll
  for (int t=0;t<2;t++){
    float bv = bias[(wave*2+t)*16 + (lane&15)];
    #pragma unroll
    for (int h=0;h<2;h++){
      acc[h][t][0]+=bv; acc[h][t][1]+=bv; acc[h][t][2]+=bv; acc[h][t][3]+=bv;
    }
  }
}

__device__ __forceinline__ fx4 mfma_g64(const u16* bP, const u16* sgb, int lane, int w4){
  fx4 acc = {0.f,0.f,0.f,0.f};
  const u16* arow = sgb + (lane&15)*SGB_P + ((lane>>4)*8);
  #pragma unroll
  for (int ks=0; ks<8; ks++){
    bs8 a = lds8(arow + ks*32);
    bs8 b = glb8(bP + (ks*4 + w4)*512 + lane*8);
    acc = MFMA16(a,b,acc);
  }
  return acc;
}

__device__ __forceinline__ void mfma_wv(const u16* wvPs, const u16* vhb2,
                                        int lane, int w4, fx4 vo[3]){
  vo[0]=(fx4){0.f,0.f,0.f,0.f}; vo[1]=vo[0]; vo[2]=vo[0];
  #pragma unroll
  for (int ks=0; ks<2; ks++){
    bs8 b = glb8(wvPs + (ks*4+w4)*512 + lane*8);
    #pragma unroll
    for (int c=0;c<3;c++){
      bs8 a = lds8(vhb2 + (c*16 + (lane&15))*XVB_P + ks*32 + ((lane>>4)*8));
      vo[c] = MFMA16(a,b,vo[c]);
    }
  }
}

// ------- k1: q/k/v/g GVPs + comp path (32 nodes / block, 8 waves) -----------
__global__ __launch_bounds__(512, 4) void k1(GP p){
  __shared__ __align__(16) u16 xsb[32*XSB_P];
  __shared__ __align__(16) u16 xvb[96*XVB_P];
  __shared__ __align__(16) u16 vhb2[96*XVB_P];
  __shared__ __align__(16) u16 sgb[32*SGB_P];
  __shared__ float red[2][8][16];
  __shared__ float redb[2][8][16];
  __shared__ float lnp[2][2][16];
  __shared__ float ubuf[32*UBUF_P];
  const int tid = threadIdx.x, lane = tid&63, wave = tid>>6;
  const int w4 = wave&3, hv = wave>>2;
  const int ml = lane&15, gl = lane>>4;
  const int n0 = blockIdx.x * 32;
  u16* xsbH  = xsb  + hv*16*XSB_P;
  u16* xvbH  = xvb  + hv*48*XVB_P;
  u16* vhb2H = vhb2 + hv*48*XVB_P;
  u16* sgbH  = sgb  + hv*16*SGB_P;

  for (int i=tid;i<2048;i+=512){
    int node=i>>6, c4=(i&63)*4;
    float4 v = *reinterpret_cast<const float4*>(p.x_s + (size_t)(n0+node)*256 + c4);
    u16* d = xsb + node*XSB_P + c4;
    d[0]=f2b(v.x); d[1]=f2b(v.y); d[2]=f2b(v.z); d[3]=f2b(v.w);
  }
  for (int i=tid;i<6144;i+=512){
    int row=i>>6, d=i&63;
    int h=row/48, rr=row-48*h, c=rr>>4, nl=rr&15;
    xvb[row*XVB_P+d] = f2b(p.x_v[(size_t)(n0+h*16+nl)*192 + d*3 + c]);
  }
  __syncthreads();

  fx4 acc[2][2];
  #pragma unroll 1
  for (int s=0; s<3; ++s){      // 0=q 1=k 2=v
    mfma_vh_vn(p.whP + s*4096, xvbH, vhb2H, xsbH, lane, w4);
    mfma_sgemm2<10>(p.wsP + (size_t)s*81920, p.wsb_f + s*256, xsb, lane, wave, acc);
    bs4 stv[2][2];
    #pragma unroll
    for (int h=0;h<2;h++){
      #pragma unroll
      for (int t=0;t<2;t++){
        int ncol=(wave*2+t)*16+ml;
        #pragma unroll
        for (int r=0;r<4;r++){
          int node16=gl*4+r;
          float v=acc[h][t][r];
          float sg=rcpf(1.f+__expf(-v));   // shared exp for sigmoid+silu
          stv[h][t][r]=(short)f2b(v*sg);
          sgb[(h*16+node16)*SGB_P+ncol]=f2b(sg);
        }
      }
    }
    __syncthreads();
    // deferred global stores: drain overlaps the g64+wv compute below
    if (s==0){
      #pragma unroll
      for (int h=0;h<2;h++)
        #pragma unroll
        for (int t=0;t<2;t++){
          int ncol=(wave*2+t)*16+ml;
          #pragma unroll
          for (int r=0;r<4;r++)
            p.QB[(size_t)(n0+h*16+gl*4+r)*448+ncol]=(u16)stv[h][t][r];
        }
    } else {
      u16* KVp = (s==1)? p.KP : p.VP;
      #pragma unroll
      for (int h=0;h<2;h++)
        #pragma unroll
        for (int t=0;t<2;t++){
          int ncol=(wave*2+t)*16+ml;
          *reinterpret_cast<bs4*>(KVp + ((size_t)((n0>>4)+h)*448 + ncol)*16 + gl*4) = stv[h][t];
        }
    }
    fx4 g = mfma_g64(p.wsvP + s*16384, sgbH, lane, w4);
    fx4 vo[3];
    mfma_wv(p.wvP + s*4096, vhb2H, lane, w4, vo);
    int dout = w4*16+ml;
    const int nb = n0 + hv*16;
    if (s==0){
      #pragma unroll
      for (int r=0;r<4;r++){
        int node=gl*4+r;
        float gg = sigm(g[r] + p.wsvb_f[dout]);
        #pragma unroll
        for (int c=0;c<3;c++)
          p.QB[(size_t)(nb+node)*448 + 256 + c*64 + dout] = f2b(vo[c][r]*gg);
      }
    } else {
      u16* KVp=(s==1)?p.KP:p.VP;
      float gg[4];
      #pragma unroll
      for (int r=0;r<4;r++) gg[r] = sigm(g[r] + p.wsvb_f[s*64+dout]);
      #pragma unroll
      for (int c=0;c<3;c++){
        bs4 st;
        #pragma unroll
        for (int r=0;r<4;r++) st[r]=(short)f2b(vo[c][r]*gg[r]);
        *reinterpret_cast<bs4*>(KVp + ((size_t)((n0>>4)+hv)*448 + 256 + c*64 + dout)*16 + gl*4) = st;
      }
    }
    __syncthreads();
  }

  // gate set
  mfma_vh_vn(p.whP + 3*4096, xvbH, vhb2H, xsbH, lane, w4);
  mfma_sgemm2<10>(p.wsP + (size_t)3*81920, p.wsb_f + 3*256, xsb, lane, wave, acc);
  {
    float psum[2][4] = {{0.f,0.f,0.f,0.f},{0.f,0.f,0.f,0.f}};
    u16 gsv[2][2][4];
    #pragma unroll
    for (int h=0;h<2;h++){
      #pragma unroll
      for (int t=0;t<2;t++){
        int ncol=(wave*2+t)*16+ml;
        float gb = p.gb_f[ncol];
        #pragma unroll
        for (int r=0;r<4;r++){
          float gs = sigm(acc[h][t][r] + gb);
          gsv[h][t][r]=f2b(gs);
          psum[h][r] += gs;
        }
      }
    }
    #pragma unroll
    for (int h=0;h<2;h++)
      #pragma unroll
      for (int r=0;r<4;r++){
        #pragma unroll
        for (int o=1;o<16;o<<=1) psum[h][r] += __shfl_xor(psum[h][r], o);
      }
    if (ml==0){
      #pragma unroll
      for (int h=0;h<2;h++)
        #pragma unroll
        for (int r=0;r<4;r++) red[h][wave][gl*4+r] = psum[h][r];
    }
    __syncthreads();
    // deferred Gs stores
    #pragma unroll
    for (int h=0;h<2;h++)
      #pragma unroll
      for (int t=0;t<2;t++){
        int ncol=(wave*2+t)*16+ml;
        #pragma unroll
        for (int r=0;r<4;r++)
          p.Gs[(size_t)(n0+h*16+gl*4+r)*256+ncol] = gsv[h][t][r];
      }
    if (tid<32){
      int h=tid>>4, nl=tid&15;
      float s8 = red[h][0][nl]+red[h][1][nl]+red[h][2][nl]+red[h][3][nl]
               + red[h][4][nl]+red[h][5][nl]+red[h][6][nl]+red[h][7][nl];
      p.Gv[n0+tid] = sigm(s8*(1.f/256.f));
    }
    __syncthreads();
  }

  // comp path
  mfma_sgemm2<8>(p.w1P, p.b1_f, xsb, lane, wave, acc);
  {
    float s1[2][4]={{0.f,0.f,0.f,0.f},{0.f,0.f,0.f,0.f}};
    float s2[2][4]={{0.f,0.f,0.f,0.f},{0.f,0.f,0.f,0.f}};
    #pragma unroll
    for (int h=0;h<2;h++)
      #pragma unroll
      for (int t=0;t<2;t++)
        #pragma unroll
        for (int r=0;r<4;r++){ float v=acc[h][t][r]; s1[h][r]+=v; s2[h][r]+=v*v; }
    #pragma unroll
    for (int h=0;h<2;h++)
      #pragma unroll
      for (int r=0;r<4;r++){
        #pragma unroll
        for (int o=1;o<16;o<<=1){ s1[h][r]+=__shfl_xor(s1[h][r],o); s2[h][r]+=__shfl_xor(s2[h][r],o); }
      }
    if (ml==0){
      #pragma unroll
      for (int h=0;h<2;h++)
        #pragma unroll
        for (int r=0;r<4;r++){
          red[h][wave][gl*4+r]=s1[h][r];
          redb[h][wave][gl*4+r]=s2[h][r];
        }
    }
    __syncthreads();
    if (tid<32){
      int h=tid>>4, nl=tid&15;
      float S1=red[h][0][nl]+red[h][1][nl]+red[h][2][nl]+red[h][3][nl]
             + red[h][4][nl]+red[h][5][nl]+red[h][6][nl]+red[h][7][nl];
      float S2=redb[h][0][nl]+redb[h][1][nl]+redb[h][2][nl]+redb[h][3][nl]
             + redb[h][4][nl]+redb[h][5][nl]+redb[h][6][nl]+redb[h][7][nl];
      float mu=S1*(1.f/256.f), var=S2*(1.f/256.f)-mu*mu;
      lnp[h][0][nl]=mu; lnp[h][1][nl]=rsqrtf(var+1e-5f);
    }
    __syncthreads();
    #pragma unroll
    for (int h=0;h<2;h++)
      #pragma unroll
      for (int t=0;t<2;t++){
        int ncol=(wave*2+t)*16+ml;
        float g=p.lng_f[ncol], b=p.lnb_f[ncol];
        #pragma unroll
        for (int r=0;r<4;r++){
          int node16=gl*4+r;
          float hh=(acc[h][t][r]-lnp[h][0][node16])*lnp[h][1][node16]*g + b;
          sgb[(h*16+node16)*SGB_P+ncol]=f2b(siluf(hh));
        }
      }
    __syncthreads();
    fx4 u = mfma_g64(p.w2P, sgbH, lane, w4);
    int rcol = w4*16+ml;
    float b2v = p.b2_f[rcol];
    #pragma unroll
    for (int r=0;r<4;r++)
      ubuf[(hv*16 + gl*4+r)*UBUF_P + rcol] = u[r] + b2v;
    __syncthreads();
    bs4 pt4;
    #pragma unroll
    for (int i=0;i<4;i++){
      int node = wave*4+i;                   // 0..31
      float uu = ubuf[node*UBUF_P + lane];
      float m = wmax(uu);
      float e = __expf(uu-m);
      float ss = wsum(e);
      pt4[i] = (short)f2b(e*rcpf(ss));
    }
    // PT[n>>4][r=lane][n&15]
    *reinterpret_cast<bs4*>(p.PT + ((size_t)((n0>>4)+(wave>>2))*64 + lane)*16 + (wave&3)*4) = pt4;
  }
}

// ---------------- k2: per-batch anchor compression via MFMA ------------------
// grid: 8 batches x {K,V} x 32 splits = 512 blocks (2/CU for latency hiding)
__device__ __forceinline__ bs8 ldfrag(const u16* base, int n8, int row, int stride){
  return *reinterpret_cast<const bs8*>(base + ((size_t)(n8>>4)*stride + row)*16 + (n8&15));
}

__global__ __launch_bounds__(256) void k2(GP p){
  const int bid = blockIdx.x;
  const int bb = bid >> 6;
  const int sv = (bid >> 5) & 1;      // 0 = K, 1 = V
  const int sp = bid & 31;
  const int lane = threadIdx.x & 63, wave = threadIdx.x >> 6;
  const int ml = lane & 15, gl = lane >> 4;
  int s0 = p.bstart[bb], s1 = p.bstart[bb+1];
  int len = s1 - s0; if (len <= 0) return;
  int cl = (((len + 31) >> 5) + 7) & ~7;       // per-split span, multiple of 8
  int kb0 = s0 + sp*cl; if (kb0 >= s1) return;
  int kb1 = kb0 + cl; if (kb1 > s1) kb1 = s1;
  int kba = kb0 & ~7;                          // 8-aligned fragment base
  const u16* F = sv ? p.VP : p.KP;
  fx4 acc[4][7];
  #pragma unroll
  for (int m=0;m<4;m++)
    #pragma unroll
    for (int t=0;t<7;t++) acc[m][t]=(fx4){0.f,0.f,0.f,0.f};

  for (int kb = kba; kb < kb1; kb += 32){
    int n8 = kb + gl*8;
    bool edge = (kb < kb0) | (kb + 32 > kb1);
    bs8 a[4];
    #pragma unroll
    for (int m=0;m<4;m++) a[m] = ldfrag(p.PT, n8, m*16+ml, 64);
    if (edge){
      #pragma unroll
      for (int j=0;j<8;j++){
        int n = n8 + j;
        if (n < kb0 || n >= kb1){
          #pragma unroll
          for (int m=0;m<4;m++) a[m][j]=0;
        }
      }
    }
    #pragma unroll
    for (int t=0;t<7;t++){
      bs8 bf = ldfrag(F, n8, (wave*7+t)*16+ml, 448);
      if (edge){
        #pragma unroll
        for (int j=0;j<8;j++){
          int n = n8 + j;
          if (n < kb0 || n >= kb1) bf[j]=0;
        }
      }
      #pragma unroll
      for (int m=0;m<4;m++) acc[m][t] = MFMA16(a[m], bf, acc[m][t]);
    }
  }
  #pragma unroll
  for (int m=0;m<4;m++){
    #pragma unroll
    for (int t=0;t<7;t++){
      int f = (wave*7+t)*16 + ml;
      int r0 = m*16 + gl*4;
      if (sv==0){
        float* dst = p.CK + ((size_t)bb*448+f)*64 + r0;
        #pragma unroll
        for (int j=0;j<4;j++) atomicAdd(dst+j, acc[m][t][j]);
      } else {
        float* dst = p.CV + ((size_t)bb*64+r0)*448 + f;
        #pragma unroll
        for (int j=0;j<4;j++) atomicAdd(dst + (size_t)j*448, acc[m][t][j]);
      }
    }
  }
}

// ------------- k2b: pack CK (with SCALE) and CV into bf16 B-fragments --------
__global__ __launch_bounds__(256) void k2b(GP p){
  int idx = blockIdx.x*256 + threadIdx.x;
  if (idx < 229376){
    int b=idx/28672, r=idx%28672;
    int ks=r/2048, r2=r%2048, nt=r2/512, r3=r2%512, ln=r3/8, j=r3&7;
    int f=ks*32+((ln>>4)*8)+j, rr=nt*16+(ln&15);
    p.CKP[idx] = f2b(p.CK[((size_t)b*448+f)*64+rr] * 0.047245559f);
    return;
  }
  idx -= 229376;
  int b=idx/28672, r=idx%28672;
  int ks=r/14336, r2=r%14336, nt=r2/512, r3=r2%512, ln=r3/8, j=r3&7;
  int rr=ks*32+((ln>>4)*8)+j, f=nt*16+(ln&15);
  p.CVP[idx] = f2b(p.CV[((size_t)b*64+rr)*448+f]);
}

// ---- k3: MFMA attention + gating + output GVP (32 nodes / block, 8 waves) ---
__global__ __launch_bounds__(512, 4) void k3(GP p){
  __shared__ __align__(16) char smem[68608];
  u16* xq   = (u16*)smem;               // phase1: [32][XQ_P]  (29184 B)
  u16* atb  = (u16*)(smem+29184);       // phase1: [32][AT_P]  (4608 B)
  u16* xsb  = (u16*)(smem+33792);       // [32][XSB_P]         (20992 B)
  u16* xvb  = (u16*)(smem+54784);       // [96][XVB_P]         (13824 B)
  u16* vhb2 = (u16*)smem;               // phase2 [96][XVB_P]  (aliases xq)
  u16* sgb  = (u16*)(smem+13824);       // phase2 [32][SGB_P]  (aliases xq tail/atb)
  __shared__ float redm[2][4][16];
  __shared__ float reds[2][4][16];
  __shared__ int Bl[32];
  const int tid = threadIdx.x;
  const int n0 = blockIdx.x * 32;
  const int lane = tid & 63, wave = tid >> 6;
  const int w4 = wave&3, hv = wave>>2;
  const int ml = lane&15, gl = lane>>4;
  const int nb = n0 + hv*16;
  u16* xqH   = xq   + hv*16*XQ_P;
  u16* atbH  = atb  + hv*16*AT_P;
  u16* xsbH  = xsb  + hv*16*XSB_P;
  u16* xvbH  = xvb  + hv*48*XVB_P;
  u16* vhb2H = vhb2 + hv*48*XVB_P;
  u16* sgbH  = sgb  + hv*16*SGB_P;
  const int* BlH = Bl + hv*16;

  // stage Q (bf16 QB rows) straight into A-fragment LDS
  for (int idx=tid; idx<1792; idx+=512){
    int node = idx/56, q = idx-node*56;
    bs8 v = *reinterpret_cast<const bs8*>(p.QB + (size_t)(n0+node)*448 + q*8);
    *reinterpret_cast<bs8*>(xq + node*XQ_P + q*8) = v;
  }
  if (tid<32) Bl[tid] = p.bidx[n0+tid];
  __syncthreads();

  // ---- attention over the block's distinct batches (usually 1) ----
  int bb = Bl[0];
  while (true){
    fx4 lac = {0.f,0.f,0.f,0.f};
    {
      const u16* ckb = p.CKP + (size_t)bb*28672;
      const u16* arow = xqH + ml*XQ_P + gl*8;
      #pragma unroll
      for (int ks=0; ks<14; ks++){
        bs8 a = lds8(arow + ks*32);
        bs8 b = glb8(ckb + (ks*4+w4)*512 + lane*8);
        lac = MFMA16(a,b,lac);
      }
    }
    // softmax over 64 anchors per node (16-lane + cross-wave reduce per half)
    float loc[4];
    #pragma unroll
    for (int r=0;r<4;r++){
      float m = lac[r];
      #pragma unroll
      for (int o=1;o<16;o<<=1) m = fmaxf(m, __shfl_xor(m,o));
      loc[r]=m;
    }
    if (ml==0){
      #pragma unroll
      for (int r=0;r<4;r++) redm[hv][w4][gl*4+r]=loc[r];
    }
    __syncthreads();
    float e4[4];
    #pragma unroll
    for (int r=0;r<4;r++){
      int node=gl*4+r;
      float gm = fmaxf(fmaxf(redm[hv][0][node],redm[hv][1][node]),
                       fmaxf(redm[hv][2][node],redm[hv][3][node]));
      float e = __expf(lac[r]-gm);
      e4[r]=e;
      float s=e;
      #pragma unroll
      for (int o=1;o<16;o<<=1) s += __shfl_xor(s,o);
      loc[r]=s;
    }
    if (ml==0){
      #pragma unroll
      for (int r=0;r<4;r++) reds[hv][w4][gl*4+r]=loc[r];
    }
    __syncthreads();
    #pragma unroll
    for (int r=0;r<4;r++){
      int node=gl*4+r;
      float tot = reds[hv][0][node]+reds[hv][1][node]+reds[hv][2][node]+reds[hv][3][node];
      atbH[node*AT_P + w4*16 + ml] = f2b(e4[r]*rcpf(tot));
    }
    __syncthreads();
    // PV: [16 nodes] x [448 features], K=64; wave handles ntiles w4*7..+6
    // stores RAW pv; gating applied in vectorized post-pass after the loop
    {
      const u16* cvb = p.CVP + (size_t)bb*28672;
      const u16* prow = atbH + ml*AT_P + gl*8;
      bs8 a0 = lds8(prow);
      bs8 a1 = lds8(prow + 32);
      #pragma unroll
      for (int t=0;t<7;t++){
        int nt = w4*7 + t;
        fx4 pv = {0.f,0.f,0.f,0.f};
        pv = MFMA16(a0, glb8(cvb + nt*512 + lane*8), pv);
        pv = MFMA16(a1, glb8(cvb + (28+nt)*512 + lane*8), pv);
        int f = nt*16 + ml;
        #pragma unroll
        for (int r=0;r<4;r++){
          int node=gl*4+r;
          if (BlH[node]!=bb) continue;
          if (f < 256){
            xsbH[node*XSB_P+f] = f2b(pv[r]);
          } else {
            int fm=f-256, c=fm>>6, d=fm&63;
            xvbH[(c*16+node)*XVB_P+d] = f2b(pv[r]);
          }
        }
      }
    }
    // next distinct batch in block (uniform across threads)
    int nxt = 0x7fffffff;
    #pragma unroll
    for (int i=0;i<32;i++){ int v=Bl[i]; if (v>bb && v<nxt) nxt=v; }
    if (nxt==0x7fffffff) break;
    bb = nxt;
    __syncthreads();   // atb rewrite hazard
  }
  __syncthreads();     // xq dead; all PV writes visible

  // vectorized gating post-pass: xsb *= Gs, xvb *= Gv
  for (int i=tid; i<1024; i+=512){
    int node=i>>5, f8=(i&31)*8;
    bs8 g8 = *reinterpret_cast<const bs8*>(p.Gs + (size_t)(n0+node)*256 + f8);
    u16* xp = xsb + node*XSB_P + f8;
    bs8 x8 = *reinterpret_cast<bs8*>(xp);
    bs8 o8;
    #pragma unroll
    for (int j=0;j<8;j++)
      o8[j] = (short)f2b(b2f((u16)x8[j]) * b2f((u16)g8[j]));
    *reinterpret_cast<bs8*>(xp) = o8;
  }
  for (int i=tid; i<768; i+=512){
    int node=i/24, g=i-node*24;
    int fm=g*8, c=fm>>6, d=fm&63;
    int row=(node>>4)*48 + c*16 + (node&15);
    float gv = p.Gv[n0+node];
    u16* xp = xvb + row*XVB_P + d;
    bs8 x8 = *reinterpret_cast<bs8*>(xp);
    bs8 o8;
    #pragma unroll
    for (int j=0;j<8;j++)
      o8[j] = (short)f2b(b2f((u16)x8[j]) * gv);
    *reinterpret_cast<bs8*>(xp) = o8;
  }
  __syncthreads();     // gated xsb/xvb ready; phase2 may overwrite xq aliases

  // output GVP (set 4 for wh/ws, set 3 for wv/wsv)
  mfma_vh_vn(p.whP + 4*4096, xvbH, vhb2H, xsbH, lane, w4);
  fx4 acc[2][2];
  mfma_sgemm2<10>(p.wsP + (size_t)4*81920, p.wsb_f + 4*256, xsb, lane, wave, acc);
  #pragma unroll
  for (int h=0;h<2;h++){
    #pragma unroll
    for (int t=0;t<2;t++){
      int ncol=(wave*2+t)*16+ml;
      #pragma unroll
      for (int r=0;r<4;r++){
        int node16=gl*4+r;
        float v=acc[h][t][r];
        float sg=rcpf(1.f+__expf(-v));     // shared exp for sigmoid+silu
        p.Qs[(size_t)(n0+h*16+node16)*256+ncol]=v*sg;
        sgb[(h*16+node16)*SGB_P+ncol]=f2b(sg);
      }
    }
  }
  __syncthreads();
  fx4 g = mfma_g64(p.wsvP + 3*16384, sgbH, lane, w4);
  fx4 vo[3];
  mfma_wv(p.wvP + 3*4096, vhb2H, lane, w4, vo);
  int dout = w4*16+ml;
  #pragma unroll
  for (int r=0;r<4;r++){
    int node=gl*4+r;
    float gg = sigm(g[r] + p.wsvb_f[3*64+dout]);
    #pragma unroll
    for (int c=0;c<3;c++)
      p.Qv[(size_t)(nb+node)*192 + dout*3 + c] = vo[c][r]*gg;   // [N,DV,3]
  }
}

// ---------------- host ------------------------------------------------------
extern "C" void kernel_launch(void* const* d_in, const int* in_sizes, int n_in,
                              void* d_out, int out_size, void* d_ws, size_t ws_size,
                              hipStream_t stream){
  (void)in_sizes; (void)n_in; (void)out_size; (void)ws_size;
  GP p;
  p.x_s  = (const float*)d_in[0];
  p.x_v  = (const float*)d_in[1];
  p.bidx = (const int*)d_in[2];
  const int whI[5]  = {3, 9, 15, 33, 21};
  const int wswI[5] = {4, 10, 16, 34, 22};
  const int wsbI[5] = {5, 11, 17, 35, 23};
  const int wvI[4]  = {6, 12, 18, 24};
  const int wsvwI[4]= {7, 13, 19, 25};
  const int wsvbI[4]= {8, 14, 20, 26};
  for (int s=0;s<5;s++){
    p.wh[s]   = (const float*)d_in[whI[s]];
    p.ws_w[s] = (const float*)d_in[wswI[s]];
    p.ws_b[s] = (const float*)d_in[wsbI[s]];
  }
  for (int s=0;s<4;s++){
    p.wv[s]    = (const float*)d_in[wvI[s]];
    p.wsv_w[s] = (const float*)d_in[wsvwI[s]];
    p.wsv_b[s] = (const float*)d_in[wsvbI[s]];
  }
  p.w1    = (const float*)d_in[27];
  p.b1    = (const float*)d_in[28];
  p.lng   = (const float*)d_in[29];
  p.lnb   = (const float*)d_in[30];
  p.w2    = (const float*)d_in[31];
  p.b2    = (const float*)d_in[32];
  p.gbias = (const float*)d_in[36];

  char* w = (char*)d_ws;
  auto alloc = [&](size_t bytes)->char*{
    char* r = w; w += (bytes + 255) & ~(size_t)255; return r;
  };
  p.wsP   = (u16*)alloc(409600u*2);
  p.whP   = (u16*)alloc(20480u*2);
  p.wvP   = (u16*)alloc(16384u*2);
  p.wsvP  = (u16*)alloc(65536u*2);
  p.w1P   = (u16*)alloc(65536u*2);
  p.w2P   = (u16*)alloc(16384u*2);
  p.wsb_f  = (float*)alloc(1280u*4);
  p.wsvb_f = (float*)alloc(256u*4);
  p.b1_f   = (float*)alloc(256u*4);
  p.b2_f   = (float*)alloc(64u*4);
  p.lng_f  = (float*)alloc(256u*4);
  p.lnb_f  = (float*)alloc(256u*4);
  p.gb_f   = (float*)alloc(256u*4);
  p.QB = (u16*)alloc((size_t)65536*448*2);
  p.KP = (u16*)alloc((size_t)65536*448*2 + (1u<<22));  // +4MB pad for masked edge reads
  p.VP = (u16*)alloc((size_t)65536*448*2 + (1u<<22));
  p.Gs = (u16*)alloc((size_t)65536*256*2);
  p.PT = (u16*)alloc((size_t)65536*64*2 + (1u<<20));
  p.Gv = (float*)alloc((size_t)65536*4);
  p.CK = (float*)alloc((size_t)8*448*64*4);
  p.CV = (float*)alloc((size_t)8*448*64*4);
  p.CKP = (u16*)alloc((size_t)8*448*64*2);
  p.CVP = (u16*)alloc((size_t)8*448*64*2);
  p.bstart = (int*)alloc(64);
  p.Qs = (float*)d_out;
  p.Qv = (float*)d_out + (size_t)65536*256;

  hipMemsetAsync(p.CK, 0, (size_t)8*448*64*4, stream);
  hipMemsetAsync(p.CV, 0, (size_t)8*448*64*4, stream);
  kprep<<<2587, 256, 0, stream>>>(p);
  k1<<<2048, 512, 0, stream>>>(p);
  k2<<<512, 256, 0, stream>>>(p);
  k2b<<<1792, 256, 0, stream>>>(p);
  k3<<<2048, 512, 0, stream>>>(p);
}